// Round 1
// baseline (298.434 us; speedup 1.0000x reference)
//
#include <hip/hip_runtime.h>
#include <cstdint>
#include <cstddef>

// Problem constants
#define BB   64
#define NN   197
#define CC   768
#define HH   12
#define THD  16          // TOTAL_HEADS
#define DD   64
#define MROWS (BB*NN)    // 12608
#define QKVN (THD*DD)    // 1024
#define SCALE_ 0.125f
#define ATTS 208         // att row stride (f32)
#define KPAD 224         // P row k-padding (7*32)

typedef unsigned short u16;
typedef __attribute__((ext_vector_type(2))) float f32x2;
typedef __attribute__((ext_vector_type(4))) float f32x4;
typedef __attribute__((ext_vector_type(8))) short s16x8;
typedef __attribute__((address_space(1))) unsigned int as1_u32;
typedef __attribute__((address_space(3))) unsigned int as3_u32;

__device__ __forceinline__ float bf2f(u16 u) {
  union { unsigned int i; float f; } x; x.i = ((unsigned int)u) << 16; return x.f;
}
__device__ __forceinline__ u16 f2bf(float f) {
  unsigned int x = __builtin_bit_cast(unsigned int, f);
  unsigned int r = (x + 0x7fffu + ((x >> 16) & 1u)) >> 16;   // RNE
  return (u16)r;
}
__device__ __forceinline__ void gl_lds16(const u16* g, u16* l) {
  __builtin_amdgcn_global_load_lds((const as1_u32*)g, (as3_u32*)l, 16, 0, 0);
}

// ---------------- x (f32) -> bf16, 8 elems/thread ---------------------------
__global__ __launch_bounds__(256) void k_cvt_x(const float* __restrict__ src,
                                               u16* __restrict__ dst, int n8) {
  int i = blockIdx.x * 256 + threadIdx.x;
  if (i >= n8) return;
  const float4* s = (const float4*)src;
  float4 a = s[2 * i], b = s[2 * i + 1];
  ushort4 lo, hi;
  lo.x = f2bf(a.x); lo.y = f2bf(a.y); lo.z = f2bf(a.z); lo.w = f2bf(a.w);
  hi.x = f2bf(b.x); hi.y = f2bf(b.y); hi.z = f2bf(b.z); hi.w = f2bf(b.w);
  ((ushort4*)dst)[2 * i] = lo;
  ((ushort4*)dst)[2 * i + 1] = hi;
}

// ---------------- weight transpose+convert f32 (R,Ccol) -> bf16 (Ccol,R) ----
__global__ __launch_bounds__(256) void k_transpose(const float* __restrict__ in,
                                                   u16* __restrict__ out,
                                                   int R, int Ccol) {
  __shared__ u16 tile[32][33];
  int c0 = blockIdx.x * 32, r0 = blockIdx.y * 32;
  int tx = threadIdx.x & 31, ty = threadIdx.x >> 5;
#pragma unroll
  for (int i = 0; i < 32; i += 8) {
    int r = r0 + ty + i, c = c0 + tx;
    tile[ty + i][tx] = (r < R && c < Ccol) ? f2bf(in[(size_t)r * Ccol + c]) : (u16)0;
  }
  __syncthreads();
#pragma unroll
  for (int i = 0; i < 32; i += 8) {
    int cc = c0 + ty + i, rr = r0 + tx;
    if (cc < Ccol && rr < R) out[(size_t)cc * R + rr] = tile[tx][ty + i];
  }
}

// ---------------- bf16 MFMA GEMM: C[M,N] = A[M,K] * Bt[N,K]^T + bias --------
// 128x128 tile, 4 waves (2x2), 16x16x32 MFMA, BK=64.
// R10: 2-phase prefetch pipeline (T3-minimum recipe): double-buffered LDS
// (64 KB, 2 blocks/CU), next K-tile's global_load_lds issued BEFORE the
// current tile's MFMA compute, ONE barrier per K-step. The __syncthreads
// vmcnt(0) drain then lands after the loads had the whole MFMA phase in
// flight — removes the per-step load-latency serialization that held the
// old blocking loop at ~325 TF (MfmaUtil 11.5%).
__global__ __launch_bounds__(256) void k_gemm_bt(const u16* __restrict__ A,
                                                 const u16* __restrict__ Bt,
                                                 const float* __restrict__ bias,
                                                 void* __restrict__ Cout,
                                                 int M, int Nn, int K,
                                                 int write_bf16) {
  __shared__ u16 As[2][2][128 * 32];   // [buf][k-half][row-chunk layout]
  __shared__ u16 Bs[2][2][128 * 32];
  int t = threadIdx.x;
  int w = t >> 6, lane = t & 63;
  int m0 = blockIdx.x * 128, n0 = blockIdx.y * 128;   // m-tile fastest (XCD locality)
  int wm = w >> 1, wn = w & 1;

  f32x4 acc[4][4];
#pragma unroll
  for (int i = 0; i < 4; i++)
#pragma unroll
    for (int j = 0; j < 4; j++)
#pragma unroll
      for (int e = 0; e < 4; e++) acc[i][j][e] = 0.f;

  int lrow4 = lane >> 2;       // 0..15
  int lkc = (lane & 3) * 8;    // 0,8,16,24

  // stage one BK=64 K-tile into buffer `buf`
  auto stage = [&](int buf, int kbase) {
#pragma unroll
    for (int half = 0; half < 2; half++) {
      int kk = kbase + half * 32;
#pragma unroll
      for (int rc = 0; rc < 2; rc++) {
        int c = w + rc * 4;                 // chunk 0..7 => rows c*16..c*16+15
        int row = c * 16 + lrow4;
        int ga = m0 + row; if (ga >= M) ga = M - 1;
        gl_lds16(A + (size_t)ga * K + kk + lkc, &As[buf][half][c * 512]);
        gl_lds16(Bt + (size_t)(n0 + row) * K + kk + lkc, &Bs[buf][half][c * 512]);
      }
    }
  };

  auto compute = [&](int buf) {
    int r16 = lane & 15, k8 = (lane >> 4) * 8;
#pragma unroll
    for (int half = 0; half < 2; half++) {
      s16x8 af[4], bfv[4];
#pragma unroll
      for (int s = 0; s < 4; s++) {
        af[s]  = *(const s16x8*)&As[buf][half][(wm * 64 + s * 16 + r16) * 32 + k8];
        bfv[s] = *(const s16x8*)&Bs[buf][half][(wn * 64 + s * 16 + r16) * 32 + k8];
      }
#pragma unroll
      for (int sm = 0; sm < 4; sm++)
#pragma unroll
        for (int sn = 0; sn < 4; sn++)
          acc[sm][sn] = __builtin_amdgcn_mfma_f32_16x16x32_bf16(af[sm], bfv[sn], acc[sm][sn], 0, 0, 0);
    }
  };

  // prologue: stage K-tile 0 into buf 0; barrier drains vmcnt(0)
  stage(0, 0);
  __syncthreads();
  int cur = 0;
  for (int k0 = 0; k0 < K; k0 += 64) {
    if (k0 + 64 < K) stage(cur ^ 1, k0 + 64);   // prefetch next tile FIRST
    compute(cur);                               // MFMA on current tile
    __syncthreads();                            // drains prefetch vmcnt + guards reuse
    cur ^= 1;
  }

  // epilogue: C/D layout col=lane&15, row=(lane>>4)*4+i
  u16*   Cb = (u16*)Cout;
  float* Cf = (float*)Cout;
  int quad = lane >> 4, col = lane & 15;
#pragma unroll
  for (int sn = 0; sn < 4; sn++) {
    int gn = n0 + wn * 64 + sn * 16 + col;
    float bv = bias[gn];
#pragma unroll
    for (int sm = 0; sm < 4; sm++) {
      int gmb = m0 + wm * 64 + sm * 16 + quad * 4;
#pragma unroll
      for (int i = 0; i < 4; i++) {
        int gm = gmb + i;
        if (gm < M) {
          float v = acc[sm][sn][i] + bv;
          if (write_bf16) Cb[(size_t)gm * Nn + gn] = f2bf(v);
          else            Cf[(size_t)gm * Nn + gn] = v;
        }
      }
    }
  }
}

// ---------------- QK^T logits via MFMA: att[bg][n][m] = SCALE * q_n . k_m ---
// One block per (n-tile 128, m-tile 128, b*2+g). K=64: ONE barrier, 32 MFMA.
__global__ __launch_bounds__(256) void k_qk(const u16* __restrict__ qkv,
                                            float* __restrict__ att) {
  __shared__ u16 As[2][128 * 32];
  __shared__ u16 Bs[2][128 * 32];
  int t = threadIdx.x;
  int w = t >> 6, lane = t & 63;
  int bz = blockIdx.z, b = bz >> 1, g = bz & 1;
  int n0 = blockIdx.x * 128;     // Q rows
  int m0 = blockIdx.y * 128;     // K rows
  int wm = w >> 1, wn = w & 1;

  f32x4 acc[4][4];
#pragma unroll
  for (int i = 0; i < 4; i++)
#pragma unroll
    for (int j = 0; j < 4; j++)
#pragma unroll
      for (int e = 0; e < 4; e++) acc[i][j][e] = 0.f;

  int lrow4 = lane >> 2, lkc = (lane & 3) * 8;

#pragma unroll
  for (int half = 0; half < 2; half++) {
    int kk = half * 32;
#pragma unroll
    for (int rc = 0; rc < 2; rc++) {
      int c = w + rc * 4;
      int row = c * 16 + lrow4;
      int nq = n0 + row; if (nq > NN - 1) nq = NN - 1;
      int mk = m0 + row; if (mk > NN - 1) mk = NN - 1;
      gl_lds16(qkv + (size_t)(b * NN + nq) * QKVN + g * DD + kk + lkc, &As[half][c * 512]);
      gl_lds16(qkv + (size_t)(b * NN + mk) * QKVN + 2 * DD + g * DD + kk + lkc, &Bs[half][c * 512]);
    }
  }
  __syncthreads();
  {
    int r16 = lane & 15, k8 = (lane >> 4) * 8;
#pragma unroll
    for (int half = 0; half < 2; half++) {
      s16x8 af[4], bfv[4];
#pragma unroll
      for (int s = 0; s < 4; s++) {
        af[s]  = *(const s16x8*)&As[half][(wm * 64 + s * 16 + r16) * 32 + k8];
        bfv[s] = *(const s16x8*)&Bs[half][(wn * 64 + s * 16 + r16) * 32 + k8];
      }
#pragma unroll
      for (int sm = 0; sm < 4; sm++)
#pragma unroll
        for (int sn = 0; sn < 4; sn++)
          acc[sm][sn] = __builtin_amdgcn_mfma_f32_16x16x32_bf16(af[sm], bfv[sn], acc[sm][sn], 0, 0, 0);
    }
  }
  int quad = lane >> 4, col = lane & 15;
#pragma unroll
  for (int sn = 0; sn < 4; sn++) {
    int gn = m0 + wn * 64 + sn * 16 + col;          // key index m
#pragma unroll
    for (int sm = 0; sm < 4; sm++) {
      int gmb = n0 + wm * 64 + sm * 16 + quad * 4;  // query index n
#pragma unroll
      for (int i = 0; i < 4; i++) {
        int gm = gmb + i;
        if (gm < NN && gn < NN)
          att[((size_t)bz * NN + gm) * ATTS + gn] = acc[sm][sn][i] * SCALE_;
      }
    }
  }
}

// ---------------- per (b,n): mask-mix + relu + head-proj + softmax -> P -----
// R9: f32x2 packed math; S[12][KPAD] tail-zeroed; f32x4 LDS reads in P-write.
__global__ __launch_bounds__(256) void k_softmax_p(const float* __restrict__ att,
                                                   const float* __restrict__ masks,
                                                   const float* __restrict__ mproj,
                                                   const float* __restrict__ mbase,
                                                   const float* __restrict__ hpw,
                                                   const float* __restrict__ hpb,
                                                   u16* __restrict__ P) {
  __shared__ float S[12][KPAD];          // 10.5 KB, tail [197,224) zeroed
  __shared__ f32x2 hpw_s[72];            // [h][k], k = h2-pair 0..5
  __shared__ f32x2 mp_s[18];             // [l][k], k = h-pair
  __shared__ f32x2 mb_s[6], hpb_s[6];
  int t = threadIdx.x;
  int n = blockIdx.x, b = blockIdx.y;

  if (t < 72) hpw_s[t] = ((const f32x2*)hpw)[t];
  if (t < 18) mp_s[t] = ((const f32x2*)mproj)[t];
  if (t < 6) { mb_s[t] = ((const f32x2*)mbase)[t]; hpb_s[t] = ((const f32x2*)hpb)[t]; }
  __syncthreads();

  if (t < NN) {
    int m = t;
    float a0 = att[((size_t)(b * 2 + 0) * NN + n) * ATTS + m];
    float a1 = att[((size_t)(b * 2 + 1) * NN + n) * ATTS + m];
    const float* mk = masks + ((size_t)n * NN + m) * 3;
    float l0 = mk[0], l1 = mk[1], l2 = mk[2];
    f32x2 pre2[6];
#pragma unroll
    for (int k = 0; k < 6; k++) {
      f32x2 wv = mb_s[k] + l0 * mp_s[k] + l1 * mp_s[6 + k] + l2 * mp_s[12 + k];
      float av = (k < 3) ? a0 : a1;
      f32x2 v = wv * av;
      pre2[k].x = v.x > 0.f ? v.x : 0.f;
      pre2[k].y = v.y > 0.f ? v.y : 0.f;
    }
    f32x2 s2[6];
#pragma unroll
    for (int k = 0; k < 6; k++) s2[k] = hpb_s[k];
#pragma unroll
    for (int h = 0; h < 12; h++) {
      float p = (h & 1) ? pre2[h >> 1].y : pre2[h >> 1].x;
#pragma unroll
      for (int k = 0; k < 6; k++) s2[k] += p * hpw_s[h * 6 + k];
    }
#pragma unroll
    for (int k = 0; k < 6; k++) {
      S[2 * k][m] = s2[k].x;
      S[2 * k + 1][m] = s2[k].y;
    }
  } else if (t < KPAD) {
#pragma unroll
    for (int h = 0; h < 12; h++) S[h][t] = 0.f;
  }
  __syncthreads();

  {  // softmax per head, 16-lane groups (verified pattern)
    int g = t >> 4, l16 = t & 15;
    if (g < 12) {
      float mx = -1e30f;
      for (int m = l16; m < NN; m += 16) mx = fmaxf(mx, S[g][m]);
#pragma unroll
      for (int off = 8; off; off >>= 1) mx = fmaxf(mx, __shfl_xor(mx, off, 16));
      float sum = 0.f;
      for (int m = l16; m < NN; m += 16) {
        float e = __expf(S[g][m] - mx);
        S[g][m] = e;
        sum += e;
      }
#pragma unroll
      for (int off = 8; off; off >>= 1) sum += __shfl_xor(sum, off, 16);
      float inv = 1.f / sum;
      for (int m = l16; m < NN; m += 16) S[g][m] *= inv;
    }
  }
  __syncthreads();

  // write P rows (bf16): 12*224/4 = 672 f32x4 chunks, no guards (tail = 0)
  for (int c4 = t; c4 < 672; c4 += 256) {
    int h = c4 / 56;                 // 56 chunks per head row
    int m = (c4 - h * 56) * 4;
    f32x4 v = *(const f32x4*)&S[h][m];
    ushort4 u;
    u.x = f2bf(v.x); u.y = f2bf(v.y); u.z = f2bf(v.z); u.w = f2bf(v.w);
    *(ushort4*)(P + ((size_t)(b * HH + h) * NN + n) * KPAD + m) = u;
  }
}

// ---------------- PV via MFMA: O[b,n,h,d] = sum_m P[b,h,n,m] V[b,m,h,d] -----
// One block per (n-tile 128, b*12+h). M=197(n) N=64(d) K=224(m). BK=64.
__global__ __launch_bounds__(256) void k_pv(const u16* __restrict__ P,
                                            const u16* __restrict__ qkv,
                                            u16* __restrict__ aout) {
  __shared__ u16 As[2][128 * 32];  // P rows [n][32 m] per half
  __shared__ u16 Bs[2][64 * 32];   // VT [d][32 m] per half
  int t = threadIdx.x;
  int w = t >> 6, lane = t & 63;
  int bh = blockIdx.y, b = bh / HH, h = bh - b * HH;
  int n0 = blockIdx.x * 128;

  f32x4 acc[2][4];
#pragma unroll
  for (int i = 0; i < 2; i++)
#pragma unroll
    for (int j = 0; j < 4; j++)
#pragma unroll
      for (int e = 0; e < 4; e++) acc[i][j][e] = 0.f;

  int lrow4 = lane >> 2, lkc = (lane & 3) * 8;
  int vml = t & 31, vd0 = (t >> 5) * 8;    // B-staging mapping

  for (int k0 = 0; k0 < KPAD; k0 += 64) {
    int nh = (KPAD - k0 >= 64) ? 2 : 1;
    for (int half = 0; half < nh; half++) {
      int kk = k0 + half * 32;
      // A: P rows via gl_lds16
#pragma unroll
      for (int rc = 0; rc < 2; rc++) {
        int c = w + rc * 4;
        int row = c * 16 + lrow4;
        int gn = n0 + row; if (gn > NN - 1) gn = NN - 1;
        gl_lds16(P + ((size_t)bh * NN + gn) * KPAD + kk + lkc, &As[half][c * 512]);
      }
      // B: V rows -> transposed LDS [d][m]
      {
        int m = kk + vml;
        u16 v8[8];
        if (m < NN) {
          const ushort4* vp = (const ushort4*)(qkv + (size_t)(b * NN + m) * QKVN + (4 + h) * DD + vd0);
          ushort4 lo = vp[0], hi = vp[1];
          v8[0] = lo.x; v8[1] = lo.y; v8[2] = lo.z; v8[3] = lo.w;
          v8[4] = hi.x; v8[5] = hi.y; v8[6] = hi.z; v8[7] = hi.w;
        } else {
#pragma unroll
          for (int j = 0; j < 8; j++) v8[j] = 0;
        }
#pragma unroll
        for (int j = 0; j < 8; j++) Bs[half][(vd0 + j) * 32 + vml] = v8[j];
      }
    }
    __syncthreads();
    int r16 = lane & 15, k8 = (lane >> 4) * 8;
    for (int half = 0; half < nh; half++) {
      s16x8 af[2], bfv[4];
#pragma unroll
      for (int s = 0; s < 2; s++)
        af[s] = *(const s16x8*)&As[half][(w * 32 + s * 16 + r16) * 32 + k8];
#pragma unroll
      for (int s = 0; s < 4; s++)
        bfv[s] = *(const s16x8*)&Bs[half][(s * 16 + r16) * 32 + k8];
#pragma unroll
      for (int sm = 0; sm < 2; sm++)
#pragma unroll
        for (int sn = 0; sn < 4; sn++)
          acc[sm][sn] = __builtin_amdgcn_mfma_f32_16x16x32_bf16(af[sm], bfv[sn], acc[sm][sn], 0, 0, 0);
    }
    __syncthreads();
  }
  int quad = lane >> 4, col = lane & 15;
#pragma unroll
  for (int sn = 0; sn < 4; sn++) {
    int gd = sn * 16 + col;                         // d
#pragma unroll
    for (int sm = 0; sm < 2; sm++) {
      int gnb = n0 + w * 32 + sm * 16 + quad * 4;   // n
#pragma unroll
      for (int i = 0; i < 4; i++) {
        int gn = gnb + i;
        if (gn < NN)
          aout[(size_t)(b * NN + gn) * CC + h * DD + gd] = f2bf(acc[sm][sn][i]);
      }
    }
  }
}

extern "C" void kernel_launch(void* const* d_in, const int* in_sizes, int n_in,
                              void* d_out, int out_size, void* d_ws, size_t ws_size,
                              hipStream_t stream) {
  const float* x     = (const float*)d_in[0];
  const float* qkv_w = (const float*)d_in[1];
  const float* qkv_b = (const float*)d_in[2];
  const float* masks = (const float*)d_in[3];
  const float* mproj = (const float*)d_in[4];
  const float* mbase = (const float*)d_in[5];
  const float* hpw   = (const float*)d_in[6];
  const float* hpb   = (const float*)d_in[7];
  const float* projw = (const float*)d_in[8];
  const float* projb = (const float*)d_in[9];

  char* ws = (char*)d_ws;
  size_t off = 0;
  auto alloc = [&](size_t bytes) {
    char* p = ws + off; off = (off + bytes + 255) & ~(size_t)255; return p;
  };
  // region1: xbf (19.4MB) -> att (21.0MB) -> aout (19.4MB), disjoint lifetimes
  char*  r1   = alloc((size_t)BB * 2 * NN * ATTS * 4);
  u16*   xbf  = (u16*)r1;
  float* att  = (float*)r1;
  u16*   aout = (u16*)r1;
  u16*   qkv  = (u16*)alloc((size_t)MROWS * QKVN * 2);          // 25.8 MB
  u16*   P    = (u16*)alloc((size_t)BB * HH * NN * KPAD * 2);   // 67.8 MB
  u16*   wt1  = (u16*)alloc((size_t)QKVN * CC * 2);             //  1.6 MB
  u16*   wt2  = (u16*)alloc((size_t)CC * CC * 2);               //  1.2 MB

  int n8 = MROWS * CC / 8;
  k_cvt_x<<<(n8 + 255) / 256, 256, 0, stream>>>(x, xbf, n8);
  k_transpose<<<dim3(QKVN / 32, CC / 32), 256, 0, stream>>>(qkv_w, wt1, CC, QKVN);
  k_transpose<<<dim3(CC / 32, CC / 32), 256, 0, stream>>>(projw, wt2, CC, CC);
  // qkv = x @ qkv_w + qkv_b  (bf16 out); grid: m-tile fastest (XCD locality)
  k_gemm_bt<<<dim3((MROWS + 127) / 128, QKVN / 128), 256, 0, stream>>>(
      xbf, wt1, qkv_b, qkv, MROWS, QKVN, CC, 1);
  // att[bg][n][m] = SCALE * q.k
  k_qk<<<dim3(2, 2, BB * 2), 256, 0, stream>>>(qkv, att);
  // P[b][h][n][m] (bf16, softmaxed)
  k_softmax_p<<<dim3(NN, BB), 256, 0, stream>>>(att, masks, mproj, mbase, hpw, hpb, P);
  // aout[b][n][h*64+d] = P @ V
  k_pv<<<dim3(2, BB * HH), 256, 0, stream>>>(P, qkv, aout);
  // out = aout @ proj_w + proj_b  (f32 out); grid: m-tile fastest
  k_gemm_bt<<<dim3((MROWS + 127) / 128, CC / 128), 256, 0, stream>>>(
      aout, wt2, projb, d_out, MROWS, CC, CC, 0);
}

// Round 2
// 284.331 us; speedup vs baseline: 1.0496x; 1.0496x over previous
//
#include <hip/hip_runtime.h>
#include <cstdint>
#include <cstddef>

// Problem constants
#define BB   64
#define NN   197
#define CC   768
#define HH   12
#define THD  16          // TOTAL_HEADS
#define DD   64
#define MROWS (BB*NN)    // 12608
#define QKVN (THD*DD)    // 1024
#define SCALE_ 0.125f
#define ATTS 208         // att row stride (f32)
#define KPAD 224         // P row k-padding (7*32)
#define SSTR 240         // S row stride (f32): 240%32=16 -> head-groups on
                         // disjoint bank halves (2-way max = free), vs 224%32=0
                         // which made all 4 groups/wave collide 4-way (4.9M conflicts)

typedef unsigned short u16;
typedef __attribute__((ext_vector_type(2))) float f32x2;
typedef __attribute__((ext_vector_type(4))) float f32x4;
typedef __attribute__((ext_vector_type(8))) short s16x8;
typedef __attribute__((address_space(1))) unsigned int as1_u32;
typedef __attribute__((address_space(3))) unsigned int as3_u32;

__device__ __forceinline__ float bf2f(u16 u) {
  union { unsigned int i; float f; } x; x.i = ((unsigned int)u) << 16; return x.f;
}
__device__ __forceinline__ u16 f2bf(float f) {
  unsigned int x = __builtin_bit_cast(unsigned int, f);
  unsigned int r = (x + 0x7fffu + ((x >> 16) & 1u)) >> 16;   // RNE
  return (u16)r;
}
__device__ __forceinline__ void gl_lds16(const u16* g, u16* l) {
  __builtin_amdgcn_global_load_lds((const as1_u32*)g, (as3_u32*)l, 16, 0, 0);
}

// ---------------- x (f32) -> bf16, 8 elems/thread ---------------------------
__global__ __launch_bounds__(256) void k_cvt_x(const float* __restrict__ src,
                                               u16* __restrict__ dst, int n8) {
  int i = blockIdx.x * 256 + threadIdx.x;
  if (i >= n8) return;
  const float4* s = (const float4*)src;
  float4 a = s[2 * i], b = s[2 * i + 1];
  ushort4 lo, hi;
  lo.x = f2bf(a.x); lo.y = f2bf(a.y); lo.z = f2bf(a.z); lo.w = f2bf(a.w);
  hi.x = f2bf(b.x); hi.y = f2bf(b.y); hi.z = f2bf(b.z); hi.w = f2bf(b.w);
  ((ushort4*)dst)[2 * i] = lo;
  ((ushort4*)dst)[2 * i + 1] = hi;
}

// ---------------- weight transpose+convert f32 (R,Ccol) -> bf16 (Ccol,R) ----
__global__ __launch_bounds__(256) void k_transpose(const float* __restrict__ in,
                                                   u16* __restrict__ out,
                                                   int R, int Ccol) {
  __shared__ u16 tile[32][33];
  int c0 = blockIdx.x * 32, r0 = blockIdx.y * 32;
  int tx = threadIdx.x & 31, ty = threadIdx.x >> 5;
#pragma unroll
  for (int i = 0; i < 32; i += 8) {
    int r = r0 + ty + i, c = c0 + tx;
    tile[ty + i][tx] = (r < R && c < Ccol) ? f2bf(in[(size_t)r * Ccol + c]) : (u16)0;
  }
  __syncthreads();
#pragma unroll
  for (int i = 0; i < 32; i += 8) {
    int cc = c0 + ty + i, rr = r0 + tx;
    if (cc < Ccol && rr < R) out[(size_t)cc * R + rr] = tile[tx][ty + i];
  }
}

// ---------------- bf16 MFMA GEMM: C[M,N] = A[M,K] * Bt[N,K]^T + bias --------
// 128x128 tile, 4 waves (2x2), 16x16x32 MFMA, BK=64.
// R10: 2-phase prefetch pipeline: double-buffered LDS (64 KB, 2 blocks/CU),
// next K-tile's global_load_lds issued BEFORE the current tile's MFMA,
// ONE barrier per K-step.
__global__ __launch_bounds__(256) void k_gemm_bt(const u16* __restrict__ A,
                                                 const u16* __restrict__ Bt,
                                                 const float* __restrict__ bias,
                                                 void* __restrict__ Cout,
                                                 int M, int Nn, int K,
                                                 int write_bf16) {
  __shared__ u16 As[2][2][128 * 32];   // [buf][k-half][row-chunk layout]
  __shared__ u16 Bs[2][2][128 * 32];
  int t = threadIdx.x;
  int w = t >> 6, lane = t & 63;
  int m0 = blockIdx.x * 128, n0 = blockIdx.y * 128;   // m-tile fastest (XCD locality)
  int wm = w >> 1, wn = w & 1;

  f32x4 acc[4][4];
#pragma unroll
  for (int i = 0; i < 4; i++)
#pragma unroll
    for (int j = 0; j < 4; j++)
#pragma unroll
      for (int e = 0; e < 4; e++) acc[i][j][e] = 0.f;

  int lrow4 = lane >> 2;       // 0..15
  int lkc = (lane & 3) * 8;    // 0,8,16,24

  // stage one BK=64 K-tile into buffer `buf`
  auto stage = [&](int buf, int kbase) {
#pragma unroll
    for (int half = 0; half < 2; half++) {
      int kk = kbase + half * 32;
#pragma unroll
      for (int rc = 0; rc < 2; rc++) {
        int c = w + rc * 4;                 // chunk 0..7 => rows c*16..c*16+15
        int row = c * 16 + lrow4;
        int ga = m0 + row; if (ga >= M) ga = M - 1;
        gl_lds16(A + (size_t)ga * K + kk + lkc, &As[buf][half][c * 512]);
        gl_lds16(Bt + (size_t)(n0 + row) * K + kk + lkc, &Bs[buf][half][c * 512]);
      }
    }
  };

  auto compute = [&](int buf) {
    int r16 = lane & 15, k8 = (lane >> 4) * 8;
#pragma unroll
    for (int half = 0; half < 2; half++) {
      s16x8 af[4], bfv[4];
#pragma unroll
      for (int s = 0; s < 4; s++) {
        af[s]  = *(const s16x8*)&As[buf][half][(wm * 64 + s * 16 + r16) * 32 + k8];
        bfv[s] = *(const s16x8*)&Bs[buf][half][(wn * 64 + s * 16 + r16) * 32 + k8];
      }
#pragma unroll
      for (int sm = 0; sm < 4; sm++)
#pragma unroll
        for (int sn = 0; sn < 4; sn++)
          acc[sm][sn] = __builtin_amdgcn_mfma_f32_16x16x32_bf16(af[sm], bfv[sn], acc[sm][sn], 0, 0, 0);
    }
  };

  // prologue: stage K-tile 0 into buf 0; barrier drains vmcnt(0)
  stage(0, 0);
  __syncthreads();
  int cur = 0;
  for (int k0 = 0; k0 < K; k0 += 64) {
    if (k0 + 64 < K) stage(cur ^ 1, k0 + 64);   // prefetch next tile FIRST
    compute(cur);                               // MFMA on current tile
    __syncthreads();                            // drains prefetch vmcnt + guards reuse
    cur ^= 1;
  }

  // epilogue: C/D layout col=lane&15, row=(lane>>4)*4+i
  u16*   Cb = (u16*)Cout;
  float* Cf = (float*)Cout;
  int quad = lane >> 4, col = lane & 15;
#pragma unroll
  for (int sn = 0; sn < 4; sn++) {
    int gn = n0 + wn * 64 + sn * 16 + col;
    float bv = bias[gn];
#pragma unroll
    for (int sm = 0; sm < 4; sm++) {
      int gmb = m0 + wm * 64 + sm * 16 + quad * 4;
#pragma unroll
      for (int i = 0; i < 4; i++) {
        int gm = gmb + i;
        if (gm < M) {
          float v = acc[sm][sn][i] + bv;
          if (write_bf16) Cb[(size_t)gm * Nn + gn] = f2bf(v);
          else            Cf[(size_t)gm * Nn + gn] = v;
        }
      }
    }
  }
}

// ---------------- QK^T logits via MFMA: att[bg][n][m] = SCALE * q_n . k_m ---
// One block per (n-tile 128, m-tile 128, b*2+g). K=64: ONE barrier, 32 MFMA.
__global__ __launch_bounds__(256) void k_qk(const u16* __restrict__ qkv,
                                            float* __restrict__ att) {
  __shared__ u16 As[2][128 * 32];
  __shared__ u16 Bs[2][128 * 32];
  int t = threadIdx.x;
  int w = t >> 6, lane = t & 63;
  int bz = blockIdx.z, b = bz >> 1, g = bz & 1;
  int n0 = blockIdx.x * 128;     // Q rows
  int m0 = blockIdx.y * 128;     // K rows
  int wm = w >> 1, wn = w & 1;

  f32x4 acc[4][4];
#pragma unroll
  for (int i = 0; i < 4; i++)
#pragma unroll
    for (int j = 0; j < 4; j++)
#pragma unroll
      for (int e = 0; e < 4; e++) acc[i][j][e] = 0.f;

  int lrow4 = lane >> 2, lkc = (lane & 3) * 8;

#pragma unroll
  for (int half = 0; half < 2; half++) {
    int kk = half * 32;
#pragma unroll
    for (int rc = 0; rc < 2; rc++) {
      int c = w + rc * 4;
      int row = c * 16 + lrow4;
      int nq = n0 + row; if (nq > NN - 1) nq = NN - 1;
      int mk = m0 + row; if (mk > NN - 1) mk = NN - 1;
      gl_lds16(qkv + (size_t)(b * NN + nq) * QKVN + g * DD + kk + lkc, &As[half][c * 512]);
      gl_lds16(qkv + (size_t)(b * NN + mk) * QKVN + 2 * DD + g * DD + kk + lkc, &Bs[half][c * 512]);
    }
  }
  __syncthreads();
  {
    int r16 = lane & 15, k8 = (lane >> 4) * 8;
#pragma unroll
    for (int half = 0; half < 2; half++) {
      s16x8 af[4], bfv[4];
#pragma unroll
      for (int s = 0; s < 4; s++) {
        af[s]  = *(const s16x8*)&As[half][(wm * 64 + s * 16 + r16) * 32 + k8];
        bfv[s] = *(const s16x8*)&Bs[half][(wn * 64 + s * 16 + r16) * 32 + k8];
      }
#pragma unroll
      for (int sm = 0; sm < 4; sm++)
#pragma unroll
        for (int sn = 0; sn < 4; sn++)
          acc[sm][sn] = __builtin_amdgcn_mfma_f32_16x16x32_bf16(af[sm], bfv[sn], acc[sm][sn], 0, 0, 0);
    }
  }
  int quad = lane >> 4, col = lane & 15;
#pragma unroll
  for (int sn = 0; sn < 4; sn++) {
    int gn = m0 + wn * 64 + sn * 16 + col;          // key index m
#pragma unroll
    for (int sm = 0; sm < 4; sm++) {
      int gmb = n0 + wm * 64 + sm * 16 + quad * 4;  // query index n
#pragma unroll
      for (int i = 0; i < 4; i++) {
        int gm = gmb + i;
        if (gm < NN && gn < NN)
          att[((size_t)bz * NN + gm) * ATTS + gn] = acc[sm][sn][i] * SCALE_;
      }
    }
  }
}

// ---------------- per (b,n): mask-mix + relu + head-proj + softmax -> P -----
// R11: S row stride 240 (kills the 4-way softmax bank conflict, 4.9M cycles),
// register-cached row in the max pass (no LDS re-read for exp), and 1/sum
// deferred to the bf16 P-write (third S pass eliminated; inv[12] in LDS).
__global__ __launch_bounds__(256) void k_softmax_p(const float* __restrict__ att,
                                                   const float* __restrict__ masks,
                                                   const float* __restrict__ mproj,
                                                   const float* __restrict__ mbase,
                                                   const float* __restrict__ hpw,
                                                   const float* __restrict__ hpb,
                                                   u16* __restrict__ P) {
  __shared__ float S[12][SSTR];          // 11.25 KB, tail [197,224) zeroed
  __shared__ f32x2 hpw_s[72];            // [h][k], k = h2-pair 0..5
  __shared__ f32x2 mp_s[18];             // [l][k], k = h-pair
  __shared__ f32x2 mb_s[6], hpb_s[6];
  __shared__ float inv_s[12];
  int t = threadIdx.x;
  int n = blockIdx.x, b = blockIdx.y;

  if (t < 72) hpw_s[t] = ((const f32x2*)hpw)[t];
  if (t < 18) mp_s[t] = ((const f32x2*)mproj)[t];
  if (t < 6) { mb_s[t] = ((const f32x2*)mbase)[t]; hpb_s[t] = ((const f32x2*)hpb)[t]; }
  __syncthreads();

  if (t < NN) {
    int m = t;
    float a0 = att[((size_t)(b * 2 + 0) * NN + n) * ATTS + m];
    float a1 = att[((size_t)(b * 2 + 1) * NN + n) * ATTS + m];
    const float* mk = masks + ((size_t)n * NN + m) * 3;
    float l0 = mk[0], l1 = mk[1], l2 = mk[2];
    f32x2 pre2[6];
#pragma unroll
    for (int k = 0; k < 6; k++) {
      f32x2 wv = mb_s[k] + l0 * mp_s[k] + l1 * mp_s[6 + k] + l2 * mp_s[12 + k];
      float av = (k < 3) ? a0 : a1;
      f32x2 v = wv * av;
      pre2[k].x = v.x > 0.f ? v.x : 0.f;
      pre2[k].y = v.y > 0.f ? v.y : 0.f;
    }
    f32x2 s2[6];
#pragma unroll
    for (int k = 0; k < 6; k++) s2[k] = hpb_s[k];
#pragma unroll
    for (int h = 0; h < 12; h++) {
      float p = (h & 1) ? pre2[h >> 1].y : pre2[h >> 1].x;
#pragma unroll
      for (int k = 0; k < 6; k++) s2[k] += p * hpw_s[h * 6 + k];
    }
#pragma unroll
    for (int k = 0; k < 6; k++) {
      S[2 * k][m] = s2[k].x;
      S[2 * k + 1][m] = s2[k].y;
    }
  } else if (t < KPAD) {
#pragma unroll
    for (int h = 0; h < 12; h++) S[h][t] = 0.f;
  }
  __syncthreads();

  {  // softmax per head, 16-lane groups; row cached in regs, 2 passes total
    int g = t >> 4, l16 = t & 15;
    if (g < 12) {
      float vals[13];
      float mx = -1e30f;
#pragma unroll
      for (int i = 0; i < 13; i++) {
        int m = l16 + i * 16;                 // <= 207 < SSTR: always in-bounds
        float x = S[g][m];
        vals[i] = (m < NN) ? x : -1e30f;
        mx = fmaxf(mx, vals[i]);
      }
#pragma unroll
      for (int off = 8; off; off >>= 1) mx = fmaxf(mx, __shfl_xor(mx, off, 16));
      float sum = 0.f;
#pragma unroll
      for (int i = 0; i < 13; i++) {
        int m = l16 + i * 16;
        float e = __expf(vals[i] - mx);       // exp(-1e30-mx) underflows to 0
        if (m < NN) { S[g][m] = e; sum += e; }
      }
#pragma unroll
      for (int off = 8; off; off >>= 1) sum += __shfl_xor(sum, off, 16);
      if (l16 == 0) inv_s[g] = 1.f / sum;
    }
  }
  __syncthreads();

  // write P rows (bf16, scaled by inv here): 12*224/4 = 672 f32x4 chunks
  for (int c4 = t; c4 < 672; c4 += 256) {
    int h = c4 / 56;                 // 56 chunks per head row
    int m = (c4 - h * 56) * 4;
    f32x4 v = *(const f32x4*)&S[h][m];
    float iv = inv_s[h];
    ushort4 u;
    u.x = f2bf(v.x * iv); u.y = f2bf(v.y * iv);
    u.z = f2bf(v.z * iv); u.w = f2bf(v.w * iv);
    *(ushort4*)(P + ((size_t)(b * HH + h) * NN + n) * KPAD + m) = u;
  }
}

// ---------------- PV via MFMA: O[b,n,h,d] = sum_m P[b,h,n,m] V[b,m,h,d] -----
// One block per (n-tile 128, b*12+h). M=197(n) N=64(d) K=224(m). BK=64.
__global__ __launch_bounds__(256) void k_pv(const u16* __restrict__ P,
                                            const u16* __restrict__ qkv,
                                            u16* __restrict__ aout) {
  __shared__ u16 As[2][128 * 32];  // P rows [n][32 m] per half
  __shared__ u16 Bs[2][64 * 32];   // VT [d][32 m] per half
  int t = threadIdx.x;
  int w = t >> 6, lane = t & 63;
  int bh = blockIdx.y, b = bh / HH, h = bh - b * HH;
  int n0 = blockIdx.x * 128;

  f32x4 acc[2][4];
#pragma unroll
  for (int i = 0; i < 2; i++)
#pragma unroll
    for (int j = 0; j < 4; j++)
#pragma unroll
      for (int e = 0; e < 4; e++) acc[i][j][e] = 0.f;

  int lrow4 = lane >> 2, lkc = (lane & 3) * 8;
  int vml = t & 31, vd0 = (t >> 5) * 8;    // B-staging mapping

  for (int k0 = 0; k0 < KPAD; k0 += 64) {
    int nh = (KPAD - k0 >= 64) ? 2 : 1;
    for (int half = 0; half < nh; half++) {
      int kk = k0 + half * 32;
      // A: P rows via gl_lds16
#pragma unroll
      for (int rc = 0; rc < 2; rc++) {
        int c = w + rc * 4;
        int row = c * 16 + lrow4;
        int gn = n0 + row; if (gn > NN - 1) gn = NN - 1;
        gl_lds16(P + ((size_t)bh * NN + gn) * KPAD + kk + lkc, &As[half][c * 512]);
      }
      // B: V rows -> transposed LDS [d][m]
      {
        int m = kk + vml;
        u16 v8[8];
        if (m < NN) {
          const ushort4* vp = (const ushort4*)(qkv + (size_t)(b * NN + m) * QKVN + (4 + h) * DD + vd0);
          ushort4 lo = vp[0], hi = vp[1];
          v8[0] = lo.x; v8[1] = lo.y; v8[2] = lo.z; v8[3] = lo.w;
          v8[4] = hi.x; v8[5] = hi.y; v8[6] = hi.z; v8[7] = hi.w;
        } else {
#pragma unroll
          for (int j = 0; j < 8; j++) v8[j] = 0;
        }
#pragma unroll
        for (int j = 0; j < 8; j++) Bs[half][(vd0 + j) * 32 + vml] = v8[j];
      }
    }
    __syncthreads();
    int r16 = lane & 15, k8 = (lane >> 4) * 8;
    for (int half = 0; half < nh; half++) {
      s16x8 af[2], bfv[4];
#pragma unroll
      for (int s = 0; s < 2; s++)
        af[s] = *(const s16x8*)&As[half][(w * 32 + s * 16 + r16) * 32 + k8];
#pragma unroll
      for (int s = 0; s < 4; s++)
        bfv[s] = *(const s16x8*)&Bs[half][(s * 16 + r16) * 32 + k8];
#pragma unroll
      for (int sm = 0; sm < 2; sm++)
#pragma unroll
        for (int sn = 0; sn < 4; sn++)
          acc[sm][sn] = __builtin_amdgcn_mfma_f32_16x16x32_bf16(af[sm], bfv[sn], acc[sm][sn], 0, 0, 0);
    }
    __syncthreads();
  }
  int quad = lane >> 4, col = lane & 15;
#pragma unroll
  for (int sn = 0; sn < 4; sn++) {
    int gd = sn * 16 + col;                         // d
#pragma unroll
    for (int sm = 0; sm < 2; sm++) {
      int gnb = n0 + w * 32 + sm * 16 + quad * 4;   // n
#pragma unroll
      for (int i = 0; i < 4; i++) {
        int gn = gnb + i;
        if (gn < NN)
          aout[(size_t)(b * NN + gn) * CC + h * DD + gd] = f2bf(acc[sm][sn][i]);
      }
    }
  }
}

extern "C" void kernel_launch(void* const* d_in, const int* in_sizes, int n_in,
                              void* d_out, int out_size, void* d_ws, size_t ws_size,
                              hipStream_t stream) {
  const float* x     = (const float*)d_in[0];
  const float* qkv_w = (const float*)d_in[1];
  const float* qkv_b = (const float*)d_in[2];
  const float* masks = (const float*)d_in[3];
  const float* mproj = (const float*)d_in[4];
  const float* mbase = (const float*)d_in[5];
  const float* hpw   = (const float*)d_in[6];
  const float* hpb   = (const float*)d_in[7];
  const float* projw = (const float*)d_in[8];
  const float* projb = (const float*)d_in[9];

  char* ws = (char*)d_ws;
  size_t off = 0;
  auto alloc = [&](size_t bytes) {
    char* p = ws + off; off = (off + bytes + 255) & ~(size_t)255; return p;
  };
  // region1: xbf (19.4MB) -> att (21.0MB) -> aout (19.4MB), disjoint lifetimes
  char*  r1   = alloc((size_t)BB * 2 * NN * ATTS * 4);
  u16*   xbf  = (u16*)r1;
  float* att  = (float*)r1;
  u16*   aout = (u16*)r1;
  u16*   qkv  = (u16*)alloc((size_t)MROWS * QKVN * 2);          // 25.8 MB
  u16*   P    = (u16*)alloc((size_t)BB * HH * NN * KPAD * 2);   // 67.8 MB
  u16*   wt1  = (u16*)alloc((size_t)QKVN * CC * 2);             //  1.6 MB
  u16*   wt2  = (u16*)alloc((size_t)CC * CC * 2);               //  1.2 MB

  int n8 = MROWS * CC / 8;
  k_cvt_x<<<(n8 + 255) / 256, 256, 0, stream>>>(x, xbf, n8);
  k_transpose<<<dim3(QKVN / 32, CC / 32), 256, 0, stream>>>(qkv_w, wt1, CC, QKVN);
  k_transpose<<<dim3(CC / 32, CC / 32), 256, 0, stream>>>(projw, wt2, CC, CC);
  // qkv = x @ qkv_w + qkv_b  (bf16 out); grid: m-tile fastest (XCD locality)
  k_gemm_bt<<<dim3((MROWS + 127) / 128, QKVN / 128), 256, 0, stream>>>(
      xbf, wt1, qkv_b, qkv, MROWS, QKVN, CC, 1);
  // att[bg][n][m] = SCALE * q.k
  k_qk<<<dim3(2, 2, BB * 2), 256, 0, stream>>>(qkv, att);
  // P[b][h][n][m] (bf16, softmaxed)
  k_softmax_p<<<dim3(NN, BB), 256, 0, stream>>>(att, masks, mproj, mbase, hpw, hpb, P);
  // aout[b][n][h*64+d] = P @ V
  k_pv<<<dim3(2, BB * HH), 256, 0, stream>>>(P, qkv, aout);
  // out = aout @ proj_w + proj_b  (f32 out); grid: m-tile fastest
  k_gemm_bt<<<dim3((MROWS + 127) / 128, CC / 128), 256, 0, stream>>>(
      aout, wt2, projb, d_out, MROWS, CC, CC, 0);
}

// Round 3
// 277.475 us; speedup vs baseline: 1.0755x; 1.0247x over previous
//
#include <hip/hip_runtime.h>
#include <cstdint>
#include <cstddef>

// Problem constants
#define BB   64
#define NN   197
#define CC   768
#define HH   12
#define THD  16          // TOTAL_HEADS
#define DD   64
#define MROWS (BB*NN)    // 12608
#define QKVN (THD*DD)    // 1024
#define SCALE_ 0.125f
#define ATTS 208         // att row stride (f32)
#define KPAD 224         // P row k-padding (7*32)
#define SSTR 240         // S row stride (f32): 240%32=16 -> 2-way max (free)

typedef unsigned short u16;
typedef __attribute__((ext_vector_type(2))) float f32x2;
typedef __attribute__((ext_vector_type(4))) float f32x4;
typedef __attribute__((ext_vector_type(8))) short s16x8;
typedef __attribute__((address_space(1))) unsigned int as1_u32;
typedef __attribute__((address_space(3))) unsigned int as3_u32;

__device__ __forceinline__ float bf2f(u16 u) {
  union { unsigned int i; float f; } x; x.i = ((unsigned int)u) << 16; return x.f;
}
__device__ __forceinline__ u16 f2bf(float f) {
  unsigned int x = __builtin_bit_cast(unsigned int, f);
  unsigned int r = (x + 0x7fffu + ((x >> 16) & 1u)) >> 16;   // RNE
  return (u16)r;
}
__device__ __forceinline__ void gl_lds16(const u16* g, u16* l) {
  __builtin_amdgcn_global_load_lds((const as1_u32*)g, (as3_u32*)l, 16, 0, 0);
}

// ---------------- x (f32) -> bf16, 8 elems/thread ---------------------------
__global__ __launch_bounds__(256) void k_cvt_x(const float* __restrict__ src,
                                               u16* __restrict__ dst, int n8) {
  int i = blockIdx.x * 256 + threadIdx.x;
  if (i >= n8) return;
  const float4* s = (const float4*)src;
  float4 a = s[2 * i], b = s[2 * i + 1];
  ushort4 lo, hi;
  lo.x = f2bf(a.x); lo.y = f2bf(a.y); lo.z = f2bf(a.z); lo.w = f2bf(a.w);
  hi.x = f2bf(b.x); hi.y = f2bf(b.y); hi.z = f2bf(b.z); hi.w = f2bf(b.w);
  ((ushort4*)dst)[2 * i] = lo;
  ((ushort4*)dst)[2 * i + 1] = hi;
}

// ---------------- weight transpose+convert f32 (R,Ccol) -> bf16 (Ccol,R) ----
__global__ __launch_bounds__(256) void k_transpose(const float* __restrict__ in,
                                                   u16* __restrict__ out,
                                                   int R, int Ccol) {
  __shared__ u16 tile[32][33];
  int c0 = blockIdx.x * 32, r0 = blockIdx.y * 32;
  int tx = threadIdx.x & 31, ty = threadIdx.x >> 5;
#pragma unroll
  for (int i = 0; i < 32; i += 8) {
    int r = r0 + ty + i, c = c0 + tx;
    tile[ty + i][tx] = (r < R && c < Ccol) ? f2bf(in[(size_t)r * Ccol + c]) : (u16)0;
  }
  __syncthreads();
#pragma unroll
  for (int i = 0; i < 32; i += 8) {
    int cc = c0 + ty + i, rr = r0 + tx;
    if (cc < Ccol && rr < R) out[(size_t)cc * R + rr] = tile[tx][ty + i];
  }
}

// ---------------- bf16 MFMA GEMM: C[M,N] = A[M,K] * Bt[N,K]^T + bias --------
// 128x128 tile, 4 waves (2x2), 16x16x32 MFMA, BK=64, double-buffered LDS,
// next-tile global_load_lds issued BEFORE current MFMA (R10).
// R12: bijective XCD-chunked block remap (T1/m204). Dispatch id d -> xcd=d%8,
// per-xcd sequence g enumerates (m-tile, n-tile) with n FASTEST, so each XCD
// owns a contiguous m-panel range with all n-tiles: concurrent working set
// ~8 A-panels (1.6MB) + full B (1.6MB) < 4MB per-XCD L2. A fetched from HBM
// once instead of 4-8x (was FETCH=82.6MB vs 21MB unique), and L2-hit gl_lds
// (~200cy) completes inside the MFMA phase, killing the per-K-step drain stall.
__global__ __launch_bounds__(256) void k_gemm_bt(const u16* __restrict__ A,
                                                 const u16* __restrict__ Bt,
                                                 const float* __restrict__ bias,
                                                 void* __restrict__ Cout,
                                                 int M, int Nn, int K,
                                                 int write_bf16) {
  __shared__ u16 As[2][2][128 * 32];   // [buf][k-half][row-chunk layout]
  __shared__ u16 Bs[2][2][128 * 32];
  int t = threadIdx.x;
  int w = t >> 6, lane = t & 63;

  // --- XCD-chunked bijective remap (m204) ---
  int NT = gridDim.y;                               // n-tiles (8 or 6)
  int nwg = gridDim.x * gridDim.y;
  int d = blockIdx.y * gridDim.x + blockIdx.x;      // dispatch index (x fastest)
  int q8 = nwg >> 3, r8 = nwg & 7;
  int xcd = d & 7, j = d >> 3;
  int g = (xcd < r8 ? xcd * (q8 + 1) : r8 * (q8 + 1) + (xcd - r8) * q8) + j;
  int mt = g / NT, nt = g - mt * NT;                // n-tile fastest within XCD chunk
  int m0 = mt * 128, n0 = nt * 128;

  int wm = w >> 1, wn = w & 1;

  f32x4 acc[4][4];
#pragma unroll
  for (int i = 0; i < 4; i++)
#pragma unroll
    for (int j2 = 0; j2 < 4; j2++)
#pragma unroll
      for (int e = 0; e < 4; e++) acc[i][j2][e] = 0.f;

  int lrow4 = lane >> 2;       // 0..15
  int lkc = (lane & 3) * 8;    // 0,8,16,24

  // stage one BK=64 K-tile into buffer `buf`
  auto stage = [&](int buf, int kbase) {
#pragma unroll
    for (int half = 0; half < 2; half++) {
      int kk = kbase + half * 32;
#pragma unroll
      for (int rc = 0; rc < 2; rc++) {
        int c = w + rc * 4;                 // chunk 0..7 => rows c*16..c*16+15
        int row = c * 16 + lrow4;
        int ga = m0 + row; if (ga >= M) ga = M - 1;
        gl_lds16(A + (size_t)ga * K + kk + lkc, &As[buf][half][c * 512]);
        gl_lds16(Bt + (size_t)(n0 + row) * K + kk + lkc, &Bs[buf][half][c * 512]);
      }
    }
  };

  auto compute = [&](int buf) {
    int r16 = lane & 15, k8 = (lane >> 4) * 8;
#pragma unroll
    for (int half = 0; half < 2; half++) {
      s16x8 af[4], bfv[4];
#pragma unroll
      for (int s = 0; s < 4; s++) {
        af[s]  = *(const s16x8*)&As[buf][half][(wm * 64 + s * 16 + r16) * 32 + k8];
        bfv[s] = *(const s16x8*)&Bs[buf][half][(wn * 64 + s * 16 + r16) * 32 + k8];
      }
#pragma unroll
      for (int sm = 0; sm < 4; sm++)
#pragma unroll
        for (int sn = 0; sn < 4; sn++)
          acc[sm][sn] = __builtin_amdgcn_mfma_f32_16x16x32_bf16(af[sm], bfv[sn], acc[sm][sn], 0, 0, 0);
    }
  };

  // prologue: stage K-tile 0 into buf 0; barrier drains vmcnt(0)
  stage(0, 0);
  __syncthreads();
  int cur = 0;
  for (int k0 = 0; k0 < K; k0 += 64) {
    if (k0 + 64 < K) stage(cur ^ 1, k0 + 64);   // prefetch next tile FIRST
    compute(cur);                               // MFMA on current tile
    __syncthreads();                            // drains prefetch vmcnt + guards reuse
    cur ^= 1;
  }

  // epilogue: C/D layout col=lane&15, row=(lane>>4)*4+i
  u16*   Cb = (u16*)Cout;
  float* Cf = (float*)Cout;
  int quad = lane >> 4, col = lane & 15;
#pragma unroll
  for (int sn = 0; sn < 4; sn++) {
    int gn = n0 + wn * 64 + sn * 16 + col;
    float bv = bias[gn];
#pragma unroll
    for (int sm = 0; sm < 4; sm++) {
      int gmb = m0 + wm * 64 + sm * 16 + quad * 4;
#pragma unroll
      for (int i = 0; i < 4; i++) {
        int gm = gmb + i;
        if (gm < M) {
          float v = acc[sm][sn][i] + bv;
          if (write_bf16) Cb[(size_t)gm * Nn + gn] = f2bf(v);
          else            Cf[(size_t)gm * Nn + gn] = v;
        }
      }
    }
  }
}

// ---------------- QK^T logits via MFMA: att[bg][n][m] = SCALE * q_n . k_m ---
// One block per (n-tile 128, m-tile 128, b*2+g). K=64: ONE barrier, 32 MFMA.
__global__ __launch_bounds__(256) void k_qk(const u16* __restrict__ qkv,
                                            float* __restrict__ att) {
  __shared__ u16 As[2][128 * 32];
  __shared__ u16 Bs[2][128 * 32];
  int t = threadIdx.x;
  int w = t >> 6, lane = t & 63;
  int bz = blockIdx.z, b = bz >> 1, g = bz & 1;
  int n0 = blockIdx.x * 128;     // Q rows
  int m0 = blockIdx.y * 128;     // K rows
  int wm = w >> 1, wn = w & 1;

  f32x4 acc[4][4];
#pragma unroll
  for (int i = 0; i < 4; i++)
#pragma unroll
    for (int j = 0; j < 4; j++)
#pragma unroll
      for (int e = 0; e < 4; e++) acc[i][j][e] = 0.f;

  int lrow4 = lane >> 2, lkc = (lane & 3) * 8;

#pragma unroll
  for (int half = 0; half < 2; half++) {
    int kk = half * 32;
#pragma unroll
    for (int rc = 0; rc < 2; rc++) {
      int c = w + rc * 4;
      int row = c * 16 + lrow4;
      int nq = n0 + row; if (nq > NN - 1) nq = NN - 1;
      int mk = m0 + row; if (mk > NN - 1) mk = NN - 1;
      gl_lds16(qkv + (size_t)(b * NN + nq) * QKVN + g * DD + kk + lkc, &As[half][c * 512]);
      gl_lds16(qkv + (size_t)(b * NN + mk) * QKVN + 2 * DD + g * DD + kk + lkc, &Bs[half][c * 512]);
    }
  }
  __syncthreads();
  {
    int r16 = lane & 15, k8 = (lane >> 4) * 8;
#pragma unroll
    for (int half = 0; half < 2; half++) {
      s16x8 af[4], bfv[4];
#pragma unroll
      for (int s = 0; s < 4; s++) {
        af[s]  = *(const s16x8*)&As[half][(wm * 64 + s * 16 + r16) * 32 + k8];
        bfv[s] = *(const s16x8*)&Bs[half][(wn * 64 + s * 16 + r16) * 32 + k8];
      }
#pragma unroll
      for (int sm = 0; sm < 4; sm++)
#pragma unroll
        for (int sn = 0; sn < 4; sn++)
          acc[sm][sn] = __builtin_amdgcn_mfma_f32_16x16x32_bf16(af[sm], bfv[sn], acc[sm][sn], 0, 0, 0);
    }
  }
  int quad = lane >> 4, col = lane & 15;
#pragma unroll
  for (int sn = 0; sn < 4; sn++) {
    int gn = m0 + wn * 64 + sn * 16 + col;          // key index m
#pragma unroll
    for (int sm = 0; sm < 4; sm++) {
      int gmb = n0 + wm * 64 + sm * 16 + quad * 4;  // query index n
#pragma unroll
      for (int i = 0; i < 4; i++) {
        int gm = gmb + i;
        if (gm < NN && gn < NN)
          att[((size_t)bz * NN + gm) * ATTS + gn] = acc[sm][sn][i] * SCALE_;
      }
    }
  }
}

// ---------------- per (b,n): mask-mix + relu + head-proj + softmax -> P -----
// R11: SSTR=240 (no 4-way softmax bank conflict), register-cached max pass,
// 1/sum deferred to the bf16 P-write (inv[12] in LDS).
__global__ __launch_bounds__(256) void k_softmax_p(const float* __restrict__ att,
                                                   const float* __restrict__ masks,
                                                   const float* __restrict__ mproj,
                                                   const float* __restrict__ mbase,
                                                   const float* __restrict__ hpw,
                                                   const float* __restrict__ hpb,
                                                   u16* __restrict__ P) {
  __shared__ float S[12][SSTR];          // 11.25 KB, tail [197,224) zeroed
  __shared__ f32x2 hpw_s[72];            // [h][k], k = h2-pair 0..5
  __shared__ f32x2 mp_s[18];             // [l][k], k = h-pair
  __shared__ f32x2 mb_s[6], hpb_s[6];
  __shared__ float inv_s[12];
  int t = threadIdx.x;
  int n = blockIdx.x, b = blockIdx.y;

  if (t < 72) hpw_s[t] = ((const f32x2*)hpw)[t];
  if (t < 18) mp_s[t] = ((const f32x2*)mproj)[t];
  if (t < 6) { mb_s[t] = ((const f32x2*)mbase)[t]; hpb_s[t] = ((const f32x2*)hpb)[t]; }
  __syncthreads();

  if (t < NN) {
    int m = t;
    float a0 = att[((size_t)(b * 2 + 0) * NN + n) * ATTS + m];
    float a1 = att[((size_t)(b * 2 + 1) * NN + n) * ATTS + m];
    const float* mk = masks + ((size_t)n * NN + m) * 3;
    float l0 = mk[0], l1 = mk[1], l2 = mk[2];
    f32x2 pre2[6];
#pragma unroll
    for (int k = 0; k < 6; k++) {
      f32x2 wv = mb_s[k] + l0 * mp_s[k] + l1 * mp_s[6 + k] + l2 * mp_s[12 + k];
      float av = (k < 3) ? a0 : a1;
      f32x2 v = wv * av;
      pre2[k].x = v.x > 0.f ? v.x : 0.f;
      pre2[k].y = v.y > 0.f ? v.y : 0.f;
    }
    f32x2 s2[6];
#pragma unroll
    for (int k = 0; k < 6; k++) s2[k] = hpb_s[k];
#pragma unroll
    for (int h = 0; h < 12; h++) {
      float p = (h & 1) ? pre2[h >> 1].y : pre2[h >> 1].x;
#pragma unroll
      for (int k = 0; k < 6; k++) s2[k] += p * hpw_s[h * 6 + k];
    }
#pragma unroll
    for (int k = 0; k < 6; k++) {
      S[2 * k][m] = s2[k].x;
      S[2 * k + 1][m] = s2[k].y;
    }
  } else if (t < KPAD) {
#pragma unroll
    for (int h = 0; h < 12; h++) S[h][t] = 0.f;
  }
  __syncthreads();

  {  // softmax per head, 16-lane groups; row cached in regs, 2 passes total
    int g = t >> 4, l16 = t & 15;
    if (g < 12) {
      float vals[13];
      float mx = -1e30f;
#pragma unroll
      for (int i = 0; i < 13; i++) {
        int m = l16 + i * 16;                 // <= 207 < SSTR: always in-bounds
        float x = S[g][m];
        vals[i] = (m < NN) ? x : -1e30f;
        mx = fmaxf(mx, vals[i]);
      }
#pragma unroll
      for (int off = 8; off; off >>= 1) mx = fmaxf(mx, __shfl_xor(mx, off, 16));
      float sum = 0.f;
#pragma unroll
      for (int i = 0; i < 13; i++) {
        int m = l16 + i * 16;
        float e = __expf(vals[i] - mx);       // exp(-1e30-mx) underflows to 0
        if (m < NN) { S[g][m] = e; sum += e; }
      }
#pragma unroll
      for (int off = 8; off; off >>= 1) sum += __shfl_xor(sum, off, 16);
      if (l16 == 0) inv_s[g] = 1.f / sum;
    }
  }
  __syncthreads();

  // write P rows (bf16, scaled by inv here): 12*224/4 = 672 f32x4 chunks
  for (int c4 = t; c4 < 672; c4 += 256) {
    int h = c4 / 56;                 // 56 chunks per head row
    int m = (c4 - h * 56) * 4;
    f32x4 v = *(const f32x4*)&S[h][m];
    float iv = inv_s[h];
    ushort4 u;
    u.x = f2bf(v.x * iv); u.y = f2bf(v.y * iv);
    u.z = f2bf(v.z * iv); u.w = f2bf(v.w * iv);
    *(ushort4*)(P + ((size_t)(b * HH + h) * NN + n) * KPAD + m) = u;
  }
}

// ---------------- PV via MFMA: O[b,n,h,d] = sum_m P[b,h,n,m] V[b,m,h,d] -----
// One block per (n-tile 128, b*12+h). M=197(n) N=64(d) K=224(m). BK=64.
__global__ __launch_bounds__(256) void k_pv(const u16* __restrict__ P,
                                            const u16* __restrict__ qkv,
                                            u16* __restrict__ aout) {
  __shared__ u16 As[2][128 * 32];  // P rows [n][32 m] per half
  __shared__ u16 Bs[2][64 * 32];   // VT [d][32 m] per half
  int t = threadIdx.x;
  int w = t >> 6, lane = t & 63;
  int bh = blockIdx.y, b = bh / HH, h = bh - b * HH;
  int n0 = blockIdx.x * 128;

  f32x4 acc[2][4];
#pragma unroll
  for (int i = 0; i < 2; i++)
#pragma unroll
    for (int j = 0; j < 4; j++)
#pragma unroll
      for (int e = 0; e < 4; e++) acc[i][j][e] = 0.f;

  int lrow4 = lane >> 2, lkc = (lane & 3) * 8;
  int vml = t & 31, vd0 = (t >> 5) * 8;    // B-staging mapping

  for (int k0 = 0; k0 < KPAD; k0 += 64) {
    int nh = (KPAD - k0 >= 64) ? 2 : 1;
    for (int half = 0; half < nh; half++) {
      int kk = k0 + half * 32;
      // A: P rows via gl_lds16
#pragma unroll
      for (int rc = 0; rc < 2; rc++) {
        int c = w + rc * 4;
        int row = c * 16 + lrow4;
        int gn = n0 + row; if (gn > NN - 1) gn = NN - 1;
        gl_lds16(P + ((size_t)bh * NN + gn) * KPAD + kk + lkc, &As[half][c * 512]);
      }
      // B: V rows -> transposed LDS [d][m]
      {
        int m = kk + vml;
        u16 v8[8];
        if (m < NN) {
          const ushort4* vp = (const ushort4*)(qkv + (size_t)(b * NN + m) * QKVN + (4 + h) * DD + vd0);
          ushort4 lo = vp[0], hi = vp[1];
          v8[0] = lo.x; v8[1] = lo.y; v8[2] = lo.z; v8[3] = lo.w;
          v8[4] = hi.x; v8[5] = hi.y; v8[6] = hi.z; v8[7] = hi.w;
        } else {
#pragma unroll
          for (int j = 0; j < 8; j++) v8[j] = 0;
        }
#pragma unroll
        for (int j = 0; j < 8; j++) Bs[half][(vd0 + j) * 32 + vml] = v8[j];
      }
    }
    __syncthreads();
    int r16 = lane & 15, k8 = (lane >> 4) * 8;
    for (int half = 0; half < nh; half++) {
      s16x8 af[2], bfv[4];
#pragma unroll
      for (int s = 0; s < 2; s++)
        af[s] = *(const s16x8*)&As[half][(w * 32 + s * 16 + r16) * 32 + k8];
#pragma unroll
      for (int s = 0; s < 4; s++)
        bfv[s] = *(const s16x8*)&Bs[half][(s * 16 + r16) * 32 + k8];
#pragma unroll
      for (int sm = 0; sm < 2; sm++)
#pragma unroll
        for (int sn = 0; sn < 4; sn++)
          acc[sm][sn] = __builtin_amdgcn_mfma_f32_16x16x32_bf16(af[sm], bfv[sn], acc[sm][sn], 0, 0, 0);
    }
    __syncthreads();
  }
  int quad = lane >> 4, col = lane & 15;
#pragma unroll
  for (int sn = 0; sn < 4; sn++) {
    int gd = sn * 16 + col;                         // d
#pragma unroll
    for (int sm = 0; sm < 2; sm++) {
      int gnb = n0 + w * 32 + sm * 16 + quad * 4;   // n
#pragma unroll
      for (int i = 0; i < 4; i++) {
        int gn = gnb + i;
        if (gn < NN)
          aout[(size_t)(b * NN + gn) * CC + h * DD + gd] = f2bf(acc[sm][sn][i]);
      }
    }
  }
}

extern "C" void kernel_launch(void* const* d_in, const int* in_sizes, int n_in,
                              void* d_out, int out_size, void* d_ws, size_t ws_size,
                              hipStream_t stream) {
  const float* x     = (const float*)d_in[0];
  const float* qkv_w = (const float*)d_in[1];
  const float* qkv_b = (const float*)d_in[2];
  const float* masks = (const float*)d_in[3];
  const float* mproj = (const float*)d_in[4];
  const float* mbase = (const float*)d_in[5];
  const float* hpw   = (const float*)d_in[6];
  const float* hpb   = (const float*)d_in[7];
  const float* projw = (const float*)d_in[8];
  const float* projb = (const float*)d_in[9];

  char* ws = (char*)d_ws;
  size_t off = 0;
  auto alloc = [&](size_t bytes) {
    char* p = ws + off; off = (off + bytes + 255) & ~(size_t)255; return p;
  };
  // region1: xbf (19.4MB) -> att (21.0MB) -> aout (19.4MB), disjoint lifetimes
  char*  r1   = alloc((size_t)BB * 2 * NN * ATTS * 4);
  u16*   xbf  = (u16*)r1;
  float* att  = (float*)r1;
  u16*   aout = (u16*)r1;
  u16*   qkv  = (u16*)alloc((size_t)MROWS * QKVN * 2);          // 25.8 MB
  u16*   P    = (u16*)alloc((size_t)BB * HH * NN * KPAD * 2);   // 67.8 MB
  u16*   wt1  = (u16*)alloc((size_t)QKVN * CC * 2);             //  1.6 MB
  u16*   wt2  = (u16*)alloc((size_t)CC * CC * 2);               //  1.2 MB

  int n8 = MROWS * CC / 8;
  k_cvt_x<<<(n8 + 255) / 256, 256, 0, stream>>>(x, xbf, n8);
  k_transpose<<<dim3(QKVN / 32, CC / 32), 256, 0, stream>>>(qkv_w, wt1, CC, QKVN);
  k_transpose<<<dim3(CC / 32, CC / 32), 256, 0, stream>>>(projw, wt2, CC, CC);
  // qkv = x @ qkv_w + qkv_b  (bf16 out); XCD-chunked remap inside kernel
  k_gemm_bt<<<dim3((MROWS + 127) / 128, QKVN / 128), 256, 0, stream>>>(
      xbf, wt1, qkv_b, qkv, MROWS, QKVN, CC, 1);
  // att[bg][n][m] = SCALE * q.k
  k_qk<<<dim3(2, 2, BB * 2), 256, 0, stream>>>(qkv, att);
  // P[b][h][n][m] (bf16, softmaxed)
  k_softmax_p<<<dim3(NN, BB), 256, 0, stream>>>(att, masks, mproj, mbase, hpw, hpb, P);
  // aout[b][n][h*64+d] = P @ V
  k_pv<<<dim3(2, BB * HH), 256, 0, stream>>>(P, qkv, aout);
  // out = aout @ proj_w + proj_b  (f32 out); XCD-chunked remap inside kernel
  k_gemm_bt<<<dim3((MROWS + 127) / 128, CC / 128), 256, 0, stream>>>(
      aout, wt2, projb, d_out, MROWS, CC, CC, 0);
}

// Round 4
// 275.746 us; speedup vs baseline: 1.0823x; 1.0063x over previous
//
#include <hip/hip_runtime.h>
#include <cstdint>
#include <cstddef>

// Problem constants
#define BB   64
#define NN   197
#define CC   768
#define HH   12
#define THD  16          // TOTAL_HEADS
#define DD   64
#define MROWS (BB*NN)    // 12608
#define QKVN (THD*DD)    // 1024
#define SCALE_ 0.125f
#define ATTS 208         // att row stride (f32)
#define KPAD 224         // P row k-padding (7*32)
#define SSTR 240         // S row stride (f32): 240%32=16 -> 2-way max (free)

typedef unsigned short u16;
typedef __attribute__((ext_vector_type(2))) float f32x2;
typedef __attribute__((ext_vector_type(4))) float f32x4;
typedef __attribute__((ext_vector_type(8))) short s16x8;
typedef __attribute__((address_space(1))) unsigned int as1_u32;
typedef __attribute__((address_space(3))) unsigned int as3_u32;

__device__ __forceinline__ float bf2f(u16 u) {
  union { unsigned int i; float f; } x; x.i = ((unsigned int)u) << 16; return x.f;
}
__device__ __forceinline__ u16 f2bf(float f) {
  unsigned int x = __builtin_bit_cast(unsigned int, f);
  unsigned int r = (x + 0x7fffu + ((x >> 16) & 1u)) >> 16;   // RNE
  return (u16)r;
}
__device__ __forceinline__ void gl_lds16(const u16* g, u16* l) {
  __builtin_amdgcn_global_load_lds((const as1_u32*)g, (as3_u32*)l, 16, 0, 0);
}

// ---------------- x (f32) -> bf16, 8 elems/thread ---------------------------
__global__ __launch_bounds__(256) void k_cvt_x(const float* __restrict__ src,
                                               u16* __restrict__ dst, int n8) {
  int i = blockIdx.x * 256 + threadIdx.x;
  if (i >= n8) return;
  const float4* s = (const float4*)src;
  float4 a = s[2 * i], b = s[2 * i + 1];
  ushort4 lo, hi;
  lo.x = f2bf(a.x); lo.y = f2bf(a.y); lo.z = f2bf(a.z); lo.w = f2bf(a.w);
  hi.x = f2bf(b.x); hi.y = f2bf(b.y); hi.z = f2bf(b.z); hi.w = f2bf(b.w);
  ((ushort4*)dst)[2 * i] = lo;
  ((ushort4*)dst)[2 * i + 1] = hi;
}

// ---------------- weight transpose+convert f32 (R,Ccol) -> bf16 (Ccol,R) ----
__global__ __launch_bounds__(256) void k_transpose(const float* __restrict__ in,
                                                   u16* __restrict__ out,
                                                   int R, int Ccol) {
  __shared__ u16 tile[32][33];
  int c0 = blockIdx.x * 32, r0 = blockIdx.y * 32;
  int tx = threadIdx.x & 31, ty = threadIdx.x >> 5;
#pragma unroll
  for (int i = 0; i < 32; i += 8) {
    int r = r0 + ty + i, c = c0 + tx;
    tile[ty + i][tx] = (r < R && c < Ccol) ? f2bf(in[(size_t)r * Ccol + c]) : (u16)0;
  }
  __syncthreads();
#pragma unroll
  for (int i = 0; i < 32; i += 8) {
    int cc = c0 + ty + i, rr = r0 + tx;
    if (cc < Ccol && rr < R) out[(size_t)cc * R + rr] = tile[tx][ty + i];
  }
}

// ---------------- bf16 MFMA GEMM: C[M,N] = A[M,K] * Bt[N,K]^T + bias --------
// R13: 256x256 tile, 8 waves (2x4), 512 threads, BK=64, 2-phase prefetch
// (verified R10 sync structure: stage-next FIRST, compute, ONE barrier).
// Rationale: at 128^2 only ~620cy of MFMA per K-step amortized the fixed
// stage-issue+drain+barrier cost (m233: ~72% overhead) and 792 blocks ran in
// 3.1 serial generations/CU. At 256^2: 200/150 blocks -> ALL resident
// (1 block/CU, 128KB LDS), 512 MFMA (~2480cy/CU) per barrier, and staging
// (64KB/K-step) comes from L2 (R12's XCD remap keeps A resident) so the
// prefetch fully lands inside the compute phase.
// LDS layout stays 64B-row subtiled [2kh][256][32] (flat [256][64] would be a
// 16-way bank conflict on ds_read_b128).
__global__ __launch_bounds__(512, 2) void k_gemm_bt(const u16* __restrict__ A,
                                                    const u16* __restrict__ Bt,
                                                    const float* __restrict__ bias,
                                                    void* __restrict__ Cout,
                                                    int M, int Nn, int K,
                                                    int write_bf16) {
  __shared__ u16 As[2][2][256 * 32];   // [buf][k-half][row*32+k] 64KB
  __shared__ u16 Bs[2][2][256 * 32];   // 64KB
  int t = threadIdx.x;
  int w = t >> 6, lane = t & 63;

  // --- XCD-chunked bijective remap (m204) ---
  int NT = gridDim.y;                               // n-tiles (4 or 3)
  int nwg = gridDim.x * gridDim.y;
  int d = blockIdx.y * gridDim.x + blockIdx.x;      // dispatch index (x fastest)
  int q8 = nwg >> 3, r8 = nwg & 7;
  int xcd = d & 7, j = d >> 3;
  int g = (xcd < r8 ? xcd * (q8 + 1) : r8 * (q8 + 1) + (xcd - r8) * q8) + j;
  int mt = g / NT, nt = g - mt * NT;                // n-tile fastest within XCD chunk
  int m0 = mt * 256, n0 = nt * 256;

  int wm = w >> 2, wn = w & 3;                      // 2 x 4 wave grid

  f32x4 acc[8][4];
#pragma unroll
  for (int i = 0; i < 8; i++)
#pragma unroll
    for (int j2 = 0; j2 < 4; j2++)
#pragma unroll
      for (int e = 0; e < 4; e++) acc[i][j2][e] = 0.f;

  int lrow4 = lane >> 2;       // 0..15
  int lkc = (lane & 3) * 8;    // 0,8,16,24

  // stage one BK=64 K-tile (A 32KB + B 32KB) into buffer `buf`:
  // chunk c = 16 rows x 32 k = 1KB = one wave-load; c = w + rc*8 (c 0..15)
  auto stage = [&](int buf, int kbase) {
#pragma unroll
    for (int kh = 0; kh < 2; kh++) {
      int kk = kbase + kh * 32;
#pragma unroll
      for (int rc = 0; rc < 2; rc++) {
        int c = w + rc * 8;                 // rows c*16..c*16+15
        int row = c * 16 + lrow4;
        int ga = m0 + row; if (ga >= M) ga = M - 1;
        gl_lds16(A + (size_t)ga * K + kk + lkc, &As[buf][kh][c * 512]);
        gl_lds16(Bt + (size_t)(n0 + row) * K + kk + lkc, &Bs[buf][kh][c * 512]);
      }
    }
  };

  auto compute = [&](int buf) {
    int r16 = lane & 15, k8 = (lane >> 4) * 8;
#pragma unroll
    for (int kh = 0; kh < 2; kh++) {
      s16x8 af[8], bfv[4];
#pragma unroll
      for (int s = 0; s < 8; s++)
        af[s]  = *(const s16x8*)&As[buf][kh][(wm * 128 + s * 16 + r16) * 32 + k8];
#pragma unroll
      for (int s = 0; s < 4; s++)
        bfv[s] = *(const s16x8*)&Bs[buf][kh][(wn * 64 + s * 16 + r16) * 32 + k8];
#pragma unroll
      for (int sm = 0; sm < 8; sm++)
#pragma unroll
        for (int sn = 0; sn < 4; sn++)
          acc[sm][sn] = __builtin_amdgcn_mfma_f32_16x16x32_bf16(af[sm], bfv[sn], acc[sm][sn], 0, 0, 0);
    }
  };

  // prologue: stage K-tile 0 into buf 0; barrier drains vmcnt(0)
  stage(0, 0);
  __syncthreads();
  int cur = 0;
  for (int k0 = 0; k0 < K; k0 += 64) {
    if (k0 + 64 < K) stage(cur ^ 1, k0 + 64);   // prefetch next tile FIRST
    compute(cur);                               // MFMA on current tile
    __syncthreads();                            // drains prefetch vmcnt + guards reuse
    cur ^= 1;
  }

  // epilogue: C/D layout col=lane&15, row=(lane>>4)*4+i
  u16*   Cb = (u16*)Cout;
  float* Cf = (float*)Cout;
  int quad = lane >> 4, col = lane & 15;
#pragma unroll
  for (int sn = 0; sn < 4; sn++) {
    int gn = n0 + wn * 64 + sn * 16 + col;
    float bv = bias[gn];
#pragma unroll
    for (int sm = 0; sm < 8; sm++) {
      int gmb = m0 + wm * 128 + sm * 16 + quad * 4;
#pragma unroll
      for (int i = 0; i < 4; i++) {
        int gm = gmb + i;
        if (gm < M) {
          float v = acc[sm][sn][i] + bv;
          if (write_bf16) Cb[(size_t)gm * Nn + gn] = f2bf(v);
          else            Cf[(size_t)gm * Nn + gn] = v;
        }
      }
    }
  }
}

// ---------------- QK^T logits via MFMA: att[bg][n][m] = SCALE * q_n . k_m ---
// One block per (n-tile 128, m-tile 128, b*2+g). K=64: ONE barrier, 32 MFMA.
__global__ __launch_bounds__(256) void k_qk(const u16* __restrict__ qkv,
                                            float* __restrict__ att) {
  __shared__ u16 As[2][128 * 32];
  __shared__ u16 Bs[2][128 * 32];
  int t = threadIdx.x;
  int w = t >> 6, lane = t & 63;
  int bz = blockIdx.z, b = bz >> 1, g = bz & 1;
  int n0 = blockIdx.x * 128;     // Q rows
  int m0 = blockIdx.y * 128;     // K rows
  int wm = w >> 1, wn = w & 1;

  f32x4 acc[4][4];
#pragma unroll
  for (int i = 0; i < 4; i++)
#pragma unroll
    for (int j = 0; j < 4; j++)
#pragma unroll
      for (int e = 0; e < 4; e++) acc[i][j][e] = 0.f;

  int lrow4 = lane >> 2, lkc = (lane & 3) * 8;

#pragma unroll
  for (int half = 0; half < 2; half++) {
    int kk = half * 32;
#pragma unroll
    for (int rc = 0; rc < 2; rc++) {
      int c = w + rc * 4;
      int row = c * 16 + lrow4;
      int nq = n0 + row; if (nq > NN - 1) nq = NN - 1;
      int mk = m0 + row; if (mk > NN - 1) mk = NN - 1;
      gl_lds16(qkv + (size_t)(b * NN + nq) * QKVN + g * DD + kk + lkc, &As[half][c * 512]);
      gl_lds16(qkv + (size_t)(b * NN + mk) * QKVN + 2 * DD + g * DD + kk + lkc, &Bs[half][c * 512]);
    }
  }
  __syncthreads();
  {
    int r16 = lane & 15, k8 = (lane >> 4) * 8;
#pragma unroll
    for (int half = 0; half < 2; half++) {
      s16x8 af[4], bfv[4];
#pragma unroll
      for (int s = 0; s < 4; s++) {
        af[s]  = *(const s16x8*)&As[half][(wm * 64 + s * 16 + r16) * 32 + k8];
        bfv[s] = *(const s16x8*)&Bs[half][(wn * 64 + s * 16 + r16) * 32 + k8];
      }
#pragma unroll
      for (int sm = 0; sm < 4; sm++)
#pragma unroll
        for (int sn = 0; sn < 4; sn++)
          acc[sm][sn] = __builtin_amdgcn_mfma_f32_16x16x32_bf16(af[sm], bfv[sn], acc[sm][sn], 0, 0, 0);
    }
  }
  int quad = lane >> 4, col = lane & 15;
#pragma unroll
  for (int sn = 0; sn < 4; sn++) {
    int gn = m0 + wn * 64 + sn * 16 + col;          // key index m
#pragma unroll
    for (int sm = 0; sm < 4; sm++) {
      int gmb = n0 + wm * 64 + sm * 16 + quad * 4;  // query index n
#pragma unroll
      for (int i = 0; i < 4; i++) {
        int gm = gmb + i;
        if (gm < NN && gn < NN)
          att[((size_t)bz * NN + gm) * ATTS + gn] = acc[sm][sn][i] * SCALE_;
      }
    }
  }
}

// ---------------- per (b,n): mask-mix + relu + head-proj + softmax -> P -----
// R11: SSTR=240 (no 4-way softmax bank conflict), register-cached max pass,
// 1/sum deferred to the bf16 P-write (inv[12] in LDS).
__global__ __launch_bounds__(256) void k_softmax_p(const float* __restrict__ att,
                                                   const float* __restrict__ masks,
                                                   const float* __restrict__ mproj,
                                                   const float* __restrict__ mbase,
                                                   const float* __restrict__ hpw,
                                                   const float* __restrict__ hpb,
                                                   u16* __restrict__ P) {
  __shared__ float S[12][SSTR];          // 11.25 KB, tail [197,224) zeroed
  __shared__ f32x2 hpw_s[72];            // [h][k], k = h2-pair 0..5
  __shared__ f32x2 mp_s[18];             // [l][k], k = h-pair
  __shared__ f32x2 mb_s[6], hpb_s[6];
  __shared__ float inv_s[12];
  int t = threadIdx.x;
  int n = blockIdx.x, b = blockIdx.y;

  if (t < 72) hpw_s[t] = ((const f32x2*)hpw)[t];
  if (t < 18) mp_s[t] = ((const f32x2*)mproj)[t];
  if (t < 6) { mb_s[t] = ((const f32x2*)mbase)[t]; hpb_s[t] = ((const f32x2*)hpb)[t]; }
  __syncthreads();

  if (t < NN) {
    int m = t;
    float a0 = att[((size_t)(b * 2 + 0) * NN + n) * ATTS + m];
    float a1 = att[((size_t)(b * 2 + 1) * NN + n) * ATTS + m];
    const float* mk = masks + ((size_t)n * NN + m) * 3;
    float l0 = mk[0], l1 = mk[1], l2 = mk[2];
    f32x2 pre2[6];
#pragma unroll
    for (int k = 0; k < 6; k++) {
      f32x2 wv = mb_s[k] + l0 * mp_s[k] + l1 * mp_s[6 + k] + l2 * mp_s[12 + k];
      float av = (k < 3) ? a0 : a1;
      f32x2 v = wv * av;
      pre2[k].x = v.x > 0.f ? v.x : 0.f;
      pre2[k].y = v.y > 0.f ? v.y : 0.f;
    }
    f32x2 s2[6];
#pragma unroll
    for (int k = 0; k < 6; k++) s2[k] = hpb_s[k];
#pragma unroll
    for (int h = 0; h < 12; h++) {
      float p = (h & 1) ? pre2[h >> 1].y : pre2[h >> 1].x;
#pragma unroll
      for (int k = 0; k < 6; k++) s2[k] += p * hpw_s[h * 6 + k];
    }
#pragma unroll
    for (int k = 0; k < 6; k++) {
      S[2 * k][m] = s2[k].x;
      S[2 * k + 1][m] = s2[k].y;
    }
  } else if (t < KPAD) {
#pragma unroll
    for (int h = 0; h < 12; h++) S[h][t] = 0.f;
  }
  __syncthreads();

  {  // softmax per head, 16-lane groups; row cached in regs, 2 passes total
    int g = t >> 4, l16 = t & 15;
    if (g < 12) {
      float vals[13];
      float mx = -1e30f;
#pragma unroll
      for (int i = 0; i < 13; i++) {
        int m = l16 + i * 16;                 // <= 207 < SSTR: always in-bounds
        float x = S[g][m];
        vals[i] = (m < NN) ? x : -1e30f;
        mx = fmaxf(mx, vals[i]);
      }
#pragma unroll
      for (int off = 8; off; off >>= 1) mx = fmaxf(mx, __shfl_xor(mx, off, 16));
      float sum = 0.f;
#pragma unroll
      for (int i = 0; i < 13; i++) {
        int m = l16 + i * 16;
        float e = __expf(vals[i] - mx);       // exp(-1e30-mx) underflows to 0
        if (m < NN) { S[g][m] = e; sum += e; }
      }
#pragma unroll
      for (int off = 8; off; off >>= 1) sum += __shfl_xor(sum, off, 16);
      if (l16 == 0) inv_s[g] = 1.f / sum;
    }
  }
  __syncthreads();

  // write P rows (bf16, scaled by inv here): 12*224/4 = 672 f32x4 chunks
  for (int c4 = t; c4 < 672; c4 += 256) {
    int h = c4 / 56;                 // 56 chunks per head row
    int m = (c4 - h * 56) * 4;
    f32x4 v = *(const f32x4*)&S[h][m];
    float iv = inv_s[h];
    ushort4 u;
    u.x = f2bf(v.x * iv); u.y = f2bf(v.y * iv);
    u.z = f2bf(v.z * iv); u.w = f2bf(v.w * iv);
    *(ushort4*)(P + ((size_t)(b * HH + h) * NN + n) * KPAD + m) = u;
  }
}

// ---------------- PV via MFMA: O[b,n,h,d] = sum_m P[b,h,n,m] V[b,m,h,d] -----
// One block per (n-tile 128, b*12+h). M=197(n) N=64(d) K=224(m). BK=64.
__global__ __launch_bounds__(256) void k_pv(const u16* __restrict__ P,
                                            const u16* __restrict__ qkv,
                                            u16* __restrict__ aout) {
  __shared__ u16 As[2][128 * 32];  // P rows [n][32 m] per half
  __shared__ u16 Bs[2][64 * 32];   // VT [d][32 m] per half
  int t = threadIdx.x;
  int w = t >> 6, lane = t & 63;
  int bh = blockIdx.y, b = bh / HH, h = bh - b * HH;
  int n0 = blockIdx.x * 128;

  f32x4 acc[2][4];
#pragma unroll
  for (int i = 0; i < 2; i++)
#pragma unroll
    for (int j = 0; j < 4; j++)
#pragma unroll
      for (int e = 0; e < 4; e++) acc[i][j][e] = 0.f;

  int lrow4 = lane >> 2, lkc = (lane & 3) * 8;
  int vml = t & 31, vd0 = (t >> 5) * 8;    // B-staging mapping

  for (int k0 = 0; k0 < KPAD; k0 += 64) {
    int nh = (KPAD - k0 >= 64) ? 2 : 1;
    for (int half = 0; half < nh; half++) {
      int kk = k0 + half * 32;
      // A: P rows via gl_lds16
#pragma unroll
      for (int rc = 0; rc < 2; rc++) {
        int c = w + rc * 4;
        int row = c * 16 + lrow4;
        int gn = n0 + row; if (gn > NN - 1) gn = NN - 1;
        gl_lds16(P + ((size_t)bh * NN + gn) * KPAD + kk + lkc, &As[half][c * 512]);
      }
      // B: V rows -> transposed LDS [d][m]
      {
        int m = kk + vml;
        u16 v8[8];
        if (m < NN) {
          const ushort4* vp = (const ushort4*)(qkv + (size_t)(b * NN + m) * QKVN + (4 + h) * DD + vd0);
          ushort4 lo = vp[0], hi = vp[1];
          v8[0] = lo.x; v8[1] = lo.y; v8[2] = lo.z; v8[3] = lo.w;
          v8[4] = hi.x; v8[5] = hi.y; v8[6] = hi.z; v8[7] = hi.w;
        } else {
#pragma unroll
          for (int j = 0; j < 8; j++) v8[j] = 0;
        }
#pragma unroll
        for (int j = 0; j < 8; j++) Bs[half][(vd0 + j) * 32 + vml] = v8[j];
      }
    }
    __syncthreads();
    int r16 = lane & 15, k8 = (lane >> 4) * 8;
    for (int half = 0; half < nh; half++) {
      s16x8 af[2], bfv[4];
#pragma unroll
      for (int s = 0; s < 2; s++)
        af[s] = *(const s16x8*)&As[half][(w * 32 + s * 16 + r16) * 32 + k8];
#pragma unroll
      for (int s = 0; s < 4; s++)
        bfv[s] = *(const s16x8*)&Bs[half][(s * 16 + r16) * 32 + k8];
#pragma unroll
      for (int sm = 0; sm < 2; sm++)
#pragma unroll
        for (int sn = 0; sn < 4; sn++)
          acc[sm][sn] = __builtin_amdgcn_mfma_f32_16x16x32_bf16(af[sm], bfv[sn], acc[sm][sn], 0, 0, 0);
    }
    __syncthreads();
  }
  int quad = lane >> 4, col = lane & 15;
#pragma unroll
  for (int sn = 0; sn < 4; sn++) {
    int gd = sn * 16 + col;                         // d
#pragma unroll
    for (int sm = 0; sm < 2; sm++) {
      int gnb = n0 + w * 32 + sm * 16 + quad * 4;   // n
#pragma unroll
      for (int i = 0; i < 4; i++) {
        int gn = gnb + i;
        if (gn < NN)
          aout[(size_t)(b * NN + gn) * CC + h * DD + gd] = f2bf(acc[sm][sn][i]);
      }
    }
  }
}

extern "C" void kernel_launch(void* const* d_in, const int* in_sizes, int n_in,
                              void* d_out, int out_size, void* d_ws, size_t ws_size,
                              hipStream_t stream) {
  const float* x     = (const float*)d_in[0];
  const float* qkv_w = (const float*)d_in[1];
  const float* qkv_b = (const float*)d_in[2];
  const float* masks = (const float*)d_in[3];
  const float* mproj = (const float*)d_in[4];
  const float* mbase = (const float*)d_in[5];
  const float* hpw   = (const float*)d_in[6];
  const float* hpb   = (const float*)d_in[7];
  const float* projw = (const float*)d_in[8];
  const float* projb = (const float*)d_in[9];

  char* ws = (char*)d_ws;
  size_t off = 0;
  auto alloc = [&](size_t bytes) {
    char* p = ws + off; off = (off + bytes + 255) & ~(size_t)255; return p;
  };
  // region1: xbf (19.4MB) -> att (21.0MB) -> aout (19.4MB), disjoint lifetimes
  char*  r1   = alloc((size_t)BB * 2 * NN * ATTS * 4);
  u16*   xbf  = (u16*)r1;
  float* att  = (float*)r1;
  u16*   aout = (u16*)r1;
  u16*   qkv  = (u16*)alloc((size_t)MROWS * QKVN * 2);          // 25.8 MB
  u16*   P    = (u16*)alloc((size_t)BB * HH * NN * KPAD * 2);   // 67.8 MB
  u16*   wt1  = (u16*)alloc((size_t)QKVN * CC * 2);             //  1.6 MB
  u16*   wt2  = (u16*)alloc((size_t)CC * CC * 2);               //  1.2 MB

  int n8 = MROWS * CC / 8;
  k_cvt_x<<<(n8 + 255) / 256, 256, 0, stream>>>(x, xbf, n8);
  k_transpose<<<dim3(QKVN / 32, CC / 32), 256, 0, stream>>>(qkv_w, wt1, CC, QKVN);
  k_transpose<<<dim3(CC / 32, CC / 32), 256, 0, stream>>>(projw, wt2, CC, CC);
  // qkv = x @ qkv_w + qkv_b  (bf16 out); 256^2 tiles, XCD-chunked remap
  k_gemm_bt<<<dim3((MROWS + 255) / 256, QKVN / 256), 512, 0, stream>>>(
      xbf, wt1, qkv_b, qkv, MROWS, QKVN, CC, 1);
  // att[bg][n][m] = SCALE * q.k
  k_qk<<<dim3(2, 2, BB * 2), 256, 0, stream>>>(qkv, att);
  // P[b][h][n][m] (bf16, softmaxed)
  k_softmax_p<<<dim3(NN, BB), 256, 0, stream>>>(att, masks, mproj, mbase, hpw, hpb, P);
  // aout[b][n][h*64+d] = P @ V
  k_pv<<<dim3(2, BB * HH), 256, 0, stream>>>(P, qkv, aout);
  // out = aout @ proj_w + proj_b  (f32 out); 256^2 tiles, XCD-chunked remap
  k_gemm_bt<<<dim3((MROWS + 255) / 256, CC / 256), 512, 0, stream>>>(
      aout, wt2, projb, d_out, MROWS, CC, CC, 0);
}

// Round 5
// 274.305 us; speedup vs baseline: 1.0880x; 1.0053x over previous
//
#include <hip/hip_runtime.h>
#include <cstdint>
#include <cstddef>

// Problem constants
#define BB   64
#define NN   197
#define CC   768
#define HH   12
#define THD  16          // TOTAL_HEADS
#define DD   64
#define MROWS (BB*NN)    // 12608
#define QKVN (THD*DD)    // 1024
#define SCALE_ 0.125f
#define ATTS 208         // att row stride (f32)
#define KPAD 224         // P row k-padding (7*32)
#define SSTR 240         // S row stride (f32): 240%32=16 -> 2-way max (free)

typedef unsigned short u16;
typedef __attribute__((ext_vector_type(2))) float f32x2;
typedef __attribute__((ext_vector_type(4))) float f32x4;
typedef __attribute__((ext_vector_type(8))) short s16x8;
typedef __attribute__((address_space(1))) unsigned int as1_u32;
typedef __attribute__((address_space(3))) unsigned int as3_u32;

__device__ __forceinline__ float bf2f(u16 u) {
  union { unsigned int i; float f; } x; x.i = ((unsigned int)u) << 16; return x.f;
}
__device__ __forceinline__ u16 f2bf(float f) {
  unsigned int x = __builtin_bit_cast(unsigned int, f);
  unsigned int r = (x + 0x7fffu + ((x >> 16) & 1u)) >> 16;   // RNE
  return (u16)r;
}
__device__ __forceinline__ void gl_lds16(const u16* g, u16* l) {
  __builtin_amdgcn_global_load_lds((const as1_u32*)g, (as3_u32*)l, 16, 0, 0);
}

// ---------------- x (f32) -> bf16, 8 elems/thread ---------------------------
__global__ __launch_bounds__(256) void k_cvt_x(const float* __restrict__ src,
                                               u16* __restrict__ dst, int n8) {
  int i = blockIdx.x * 256 + threadIdx.x;
  if (i >= n8) return;
  const float4* s = (const float4*)src;
  float4 a = s[2 * i], b = s[2 * i + 1];
  ushort4 lo, hi;
  lo.x = f2bf(a.x); lo.y = f2bf(a.y); lo.z = f2bf(a.z); lo.w = f2bf(a.w);
  hi.x = f2bf(b.x); hi.y = f2bf(b.y); hi.z = f2bf(b.z); hi.w = f2bf(b.w);
  ((ushort4*)dst)[2 * i] = lo;
  ((ushort4*)dst)[2 * i + 1] = hi;
}

// ---------------- weight transpose+convert f32 (R,Ccol) -> bf16 (Ccol,R) ----
__global__ __launch_bounds__(256) void k_transpose(const float* __restrict__ in,
                                                   u16* __restrict__ out,
                                                   int R, int Ccol) {
  __shared__ u16 tile[32][33];
  int c0 = blockIdx.x * 32, r0 = blockIdx.y * 32;
  int tx = threadIdx.x & 31, ty = threadIdx.x >> 5;
#pragma unroll
  for (int i = 0; i < 32; i += 8) {
    int r = r0 + ty + i, c = c0 + tx;
    tile[ty + i][tx] = (r < R && c < Ccol) ? f2bf(in[(size_t)r * Ccol + c]) : (u16)0;
  }
  __syncthreads();
#pragma unroll
  for (int i = 0; i < 32; i += 8) {
    int cc = c0 + ty + i, rr = r0 + tx;
    if (cc < Ccol && rr < R) out[(size_t)cc * R + rr] = tile[tx][ty + i];
  }
}

// ---------------- bf16 MFMA GEMM: C[M,N] = A[M,K] * Bt[N,K]^T + bias --------
// R14: counted-vmcnt pipeline (T4). 256x256 tile, 8 waves (2x4), BK=32,
// TRIPLE-buffered LDS (3 x 32 KB = 96 KB), loads issued 2 K-steps ahead.
// Per step: { stage(t+2) ; s_waitcnt vmcnt(8) ; s_barrier ; ds_read+MFMA ;
// s_barrier }. vmcnt(8) (4 loads/thread/tile, 3 tiles in flight) guarantees
// this wave's tile-t loads complete (in-order, m135); the FOLLOWING barrier
// propagates that to all waves, so post-barrier reads are race-free. The
// end-of-step barrier orders all reads of buf t%3 before its re-stage at t+1.
// Raw s_barrier (NOT __syncthreads) avoids the compiler's vmcnt(0) drain —
// the drain was the R10/R13 stall (m218: 2-phase-with-drain0 == no pipeline).
// sched_barrier(0) after inline-asm waits per rule #18.
__global__ __launch_bounds__(512, 2) void k_gemm_bt(const u16* __restrict__ A,
                                                    const u16* __restrict__ Bt,
                                                    const float* __restrict__ bias,
                                                    void* __restrict__ Cout,
                                                    int M, int Nn, int K,
                                                    int write_bf16) {
  __shared__ u16 As[3][256 * 32];   // [buf][row*32 + k], 16 KB per buf
  __shared__ u16 Bs[3][256 * 32];
  int t = threadIdx.x;
  int w = t >> 6, lane = t & 63;

  // --- XCD-chunked bijective remap (m204) ---
  int NT = gridDim.y;                               // n-tiles (4 or 3)
  int nwg = gridDim.x * gridDim.y;
  int d = blockIdx.y * gridDim.x + blockIdx.x;      // dispatch index (x fastest)
  int q8 = nwg >> 3, r8 = nwg & 7;
  int xcd = d & 7, j = d >> 3;
  int g = (xcd < r8 ? xcd * (q8 + 1) : r8 * (q8 + 1) + (xcd - r8) * q8) + j;
  int mt = g / NT, nt_ = g - mt * NT;               // n-tile fastest within XCD chunk
  int m0 = mt * 256, n0 = nt_ * 256;

  int wm = w >> 2, wn = w & 3;                      // 2 x 4 wave grid

  f32x4 acc[8][4];
#pragma unroll
  for (int i = 0; i < 8; i++)
#pragma unroll
    for (int j2 = 0; j2 < 4; j2++)
#pragma unroll
      for (int e = 0; e < 4; e++) acc[i][j2][e] = 0.f;

  int lrow4 = lane >> 2;       // 0..15
  int lkc = (lane & 3) * 8;    // 0,8,16,24

  // stage one BK=32 K-tile (A 16KB + B 16KB) into buffer `buf`.
  // chunk = 16 rows x 32 k = 1 KB = one wave gl_lds; c = w + rc*8 (0..15).
  // 4 VMEM instructions per thread per tile (2 A + 2 B).
  auto stage = [&](int buf, int kk) {
#pragma unroll
    for (int rc = 0; rc < 2; rc++) {
      int c = w + rc * 8;
      int row = c * 16 + lrow4;
      int ga = m0 + row; if (ga >= M) ga = M - 1;
      gl_lds16(A + (size_t)ga * K + kk + lkc, &As[buf][c * 512]);
      gl_lds16(Bt + (size_t)(n0 + row) * K + kk + lkc, &Bs[buf][c * 512]);
    }
  };

  auto compute = [&](int buf) {
    int r16 = lane & 15, k8 = (lane >> 4) * 8;
    s16x8 af[8], bfv[4];
#pragma unroll
    for (int s = 0; s < 8; s++)
      af[s] = *(const s16x8*)&As[buf][(wm * 128 + s * 16 + r16) * 32 + k8];
#pragma unroll
    for (int s = 0; s < 4; s++)
      bfv[s] = *(const s16x8*)&Bs[buf][(wn * 64 + s * 16 + r16) * 32 + k8];
#pragma unroll
    for (int sm = 0; sm < 8; sm++)
#pragma unroll
      for (int sn = 0; sn < 4; sn++)
        acc[sm][sn] = __builtin_amdgcn_mfma_f32_16x16x32_bf16(af[sm], bfv[sn], acc[sm][sn], 0, 0, 0);
  };

  int nt = K >> 5;                  // 24 for K=768
  // prologue: tiles 0 and 1 in flight (8 VMEM/thread outstanding)
  stage(0, 0);
  stage(1, 32);
  // main loop: steady-state depth-2 prefetch, vmcnt(8) = tiles t+1,t+2 allowed
  for (int tt = 0; tt < nt - 2; ++tt) {
    stage((tt + 2) % 3, (tt + 2) * 32);
    asm volatile("s_waitcnt vmcnt(8)" ::: "memory");
    __builtin_amdgcn_sched_barrier(0);
    __builtin_amdgcn_s_barrier();
    compute(tt % 3);
    __builtin_amdgcn_s_barrier();
  }
  // peeled step nt-2: no stage; tile nt-1 (4 loads) may remain in flight
  asm volatile("s_waitcnt vmcnt(4)" ::: "memory");
  __builtin_amdgcn_sched_barrier(0);
  __builtin_amdgcn_s_barrier();
  compute((nt - 2) % 3);
  __builtin_amdgcn_s_barrier();
  // peeled step nt-1: drain everything
  asm volatile("s_waitcnt vmcnt(0)" ::: "memory");
  __builtin_amdgcn_sched_barrier(0);
  __builtin_amdgcn_s_barrier();
  compute((nt - 1) % 3);

  // epilogue: C/D layout col=lane&15, row=(lane>>4)*4+i
  u16*   Cb = (u16*)Cout;
  float* Cf = (float*)Cout;
  int quad = lane >> 4, col = lane & 15;
#pragma unroll
  for (int sn = 0; sn < 4; sn++) {
    int gn = n0 + wn * 64 + sn * 16 + col;
    float bv = bias[gn];
#pragma unroll
    for (int sm = 0; sm < 8; sm++) {
      int gmb = m0 + wm * 128 + sm * 16 + quad * 4;
#pragma unroll
      for (int i = 0; i < 4; i++) {
        int gm = gmb + i;
        if (gm < M) {
          float v = acc[sm][sn][i] + bv;
          if (write_bf16) Cb[(size_t)gm * Nn + gn] = f2bf(v);
          else            Cf[(size_t)gm * Nn + gn] = v;
        }
      }
    }
  }
}

// ---------------- QK^T logits via MFMA: att[bg][n][m] = SCALE * q_n . k_m ---
// One block per (n-tile 128, m-tile 128, b*2+g). K=64: ONE barrier, 32 MFMA.
__global__ __launch_bounds__(256) void k_qk(const u16* __restrict__ qkv,
                                            float* __restrict__ att) {
  __shared__ u16 As[2][128 * 32];
  __shared__ u16 Bs[2][128 * 32];
  int t = threadIdx.x;
  int w = t >> 6, lane = t & 63;
  int bz = blockIdx.z, b = bz >> 1, g = bz & 1;
  int n0 = blockIdx.x * 128;     // Q rows
  int m0 = blockIdx.y * 128;     // K rows
  int wm = w >> 1, wn = w & 1;

  f32x4 acc[4][4];
#pragma unroll
  for (int i = 0; i < 4; i++)
#pragma unroll
    for (int j = 0; j < 4; j++)
#pragma unroll
      for (int e = 0; e < 4; e++) acc[i][j][e] = 0.f;

  int lrow4 = lane >> 2, lkc = (lane & 3) * 8;

#pragma unroll
  for (int half = 0; half < 2; half++) {
    int kk = half * 32;
#pragma unroll
    for (int rc = 0; rc < 2; rc++) {
      int c = w + rc * 4;
      int row = c * 16 + lrow4;
      int nq = n0 + row; if (nq > NN - 1) nq = NN - 1;
      int mk = m0 + row; if (mk > NN - 1) mk = NN - 1;
      gl_lds16(qkv + (size_t)(b * NN + nq) * QKVN + g * DD + kk + lkc, &As[half][c * 512]);
      gl_lds16(qkv + (size_t)(b * NN + mk) * QKVN + 2 * DD + g * DD + kk + lkc, &Bs[half][c * 512]);
    }
  }
  __syncthreads();
  {
    int r16 = lane & 15, k8 = (lane >> 4) * 8;
#pragma unroll
    for (int half = 0; half < 2; half++) {
      s16x8 af[4], bfv[4];
#pragma unroll
      for (int s = 0; s < 4; s++) {
        af[s]  = *(const s16x8*)&As[half][(wm * 64 + s * 16 + r16) * 32 + k8];
        bfv[s] = *(const s16x8*)&Bs[half][(wn * 64 + s * 16 + r16) * 32 + k8];
      }
#pragma unroll
      for (int sm = 0; sm < 4; sm++)
#pragma unroll
        for (int sn = 0; sn < 4; sn++)
          acc[sm][sn] = __builtin_amdgcn_mfma_f32_16x16x32_bf16(af[sm], bfv[sn], acc[sm][sn], 0, 0, 0);
    }
  }
  int quad = lane >> 4, col = lane & 15;
#pragma unroll
  for (int sn = 0; sn < 4; sn++) {
    int gn = m0 + wn * 64 + sn * 16 + col;          // key index m
#pragma unroll
    for (int sm = 0; sm < 4; sm++) {
      int gmb = n0 + wm * 64 + sm * 16 + quad * 4;  // query index n
#pragma unroll
      for (int i = 0; i < 4; i++) {
        int gm = gmb + i;
        if (gm < NN && gn < NN)
          att[((size_t)bz * NN + gm) * ATTS + gn] = acc[sm][sn][i] * SCALE_;
      }
    }
  }
}

// ---------------- per (b,n): mask-mix + relu + head-proj + softmax -> P -----
// R11: SSTR=240 (no 4-way softmax bank conflict), register-cached max pass,
// 1/sum deferred to the bf16 P-write (inv[12] in LDS).
__global__ __launch_bounds__(256) void k_softmax_p(const float* __restrict__ att,
                                                   const float* __restrict__ masks,
                                                   const float* __restrict__ mproj,
                                                   const float* __restrict__ mbase,
                                                   const float* __restrict__ hpw,
                                                   const float* __restrict__ hpb,
                                                   u16* __restrict__ P) {
  __shared__ float S[12][SSTR];          // 11.25 KB, tail [197,224) zeroed
  __shared__ f32x2 hpw_s[72];            // [h][k], k = h2-pair 0..5
  __shared__ f32x2 mp_s[18];             // [l][k], k = h-pair
  __shared__ f32x2 mb_s[6], hpb_s[6];
  __shared__ float inv_s[12];
  int t = threadIdx.x;
  int n = blockIdx.x, b = blockIdx.y;

  if (t < 72) hpw_s[t] = ((const f32x2*)hpw)[t];
  if (t < 18) mp_s[t] = ((const f32x2*)mproj)[t];
  if (t < 6) { mb_s[t] = ((const f32x2*)mbase)[t]; hpb_s[t] = ((const f32x2*)hpb)[t]; }
  __syncthreads();

  if (t < NN) {
    int m = t;
    float a0 = att[((size_t)(b * 2 + 0) * NN + n) * ATTS + m];
    float a1 = att[((size_t)(b * 2 + 1) * NN + n) * ATTS + m];
    const float* mk = masks + ((size_t)n * NN + m) * 3;
    float l0 = mk[0], l1 = mk[1], l2 = mk[2];
    f32x2 pre2[6];
#pragma unroll
    for (int k = 0; k < 6; k++) {
      f32x2 wv = mb_s[k] + l0 * mp_s[k] + l1 * mp_s[6 + k] + l2 * mp_s[12 + k];
      float av = (k < 3) ? a0 : a1;
      f32x2 v = wv * av;
      pre2[k].x = v.x > 0.f ? v.x : 0.f;
      pre2[k].y = v.y > 0.f ? v.y : 0.f;
    }
    f32x2 s2[6];
#pragma unroll
    for (int k = 0; k < 6; k++) s2[k] = hpb_s[k];
#pragma unroll
    for (int h = 0; h < 12; h++) {
      float p = (h & 1) ? pre2[h >> 1].y : pre2[h >> 1].x;
#pragma unroll
      for (int k = 0; k < 6; k++) s2[k] += p * hpw_s[h * 6 + k];
    }
#pragma unroll
    for (int k = 0; k < 6; k++) {
      S[2 * k][m] = s2[k].x;
      S[2 * k + 1][m] = s2[k].y;
    }
  } else if (t < KPAD) {
#pragma unroll
    for (int h = 0; h < 12; h++) S[h][t] = 0.f;
  }
  __syncthreads();

  {  // softmax per head, 16-lane groups; row cached in regs, 2 passes total
    int g = t >> 4, l16 = t & 15;
    if (g < 12) {
      float vals[13];
      float mx = -1e30f;
#pragma unroll
      for (int i = 0; i < 13; i++) {
        int m = l16 + i * 16;                 // <= 207 < SSTR: always in-bounds
        float x = S[g][m];
        vals[i] = (m < NN) ? x : -1e30f;
        mx = fmaxf(mx, vals[i]);
      }
#pragma unroll
      for (int off = 8; off; off >>= 1) mx = fmaxf(mx, __shfl_xor(mx, off, 16));
      float sum = 0.f;
#pragma unroll
      for (int i = 0; i < 13; i++) {
        int m = l16 + i * 16;
        float e = __expf(vals[i] - mx);       // exp(-1e30-mx) underflows to 0
        if (m < NN) { S[g][m] = e; sum += e; }
      }
#pragma unroll
      for (int off = 8; off; off >>= 1) sum += __shfl_xor(sum, off, 16);
      if (l16 == 0) inv_s[g] = 1.f / sum;
    }
  }
  __syncthreads();

  // write P rows (bf16, scaled by inv here): 12*224/4 = 672 f32x4 chunks
  for (int c4 = t; c4 < 672; c4 += 256) {
    int h = c4 / 56;                 // 56 chunks per head row
    int m = (c4 - h * 56) * 4;
    f32x4 v = *(const f32x4*)&S[h][m];
    float iv = inv_s[h];
    ushort4 u;
    u.x = f2bf(v.x * iv); u.y = f2bf(v.y * iv);
    u.z = f2bf(v.z * iv); u.w = f2bf(v.w * iv);
    *(ushort4*)(P + ((size_t)(b * HH + h) * NN + n) * KPAD + m) = u;
  }
}

// ---------------- PV via MFMA: O[b,n,h,d] = sum_m P[b,h,n,m] V[b,m,h,d] -----
// One block per (n-tile 128, b*12+h). M=197(n) N=64(d) K=224(m). BK=64.
__global__ __launch_bounds__(256) void k_pv(const u16* __restrict__ P,
                                            const u16* __restrict__ qkv,
                                            u16* __restrict__ aout) {
  __shared__ u16 As[2][128 * 32];  // P rows [n][32 m] per half
  __shared__ u16 Bs[2][64 * 32];   // VT [d][32 m] per half
  int t = threadIdx.x;
  int w = t >> 6, lane = t & 63;
  int bh = blockIdx.y, b = bh / HH, h = bh - b * HH;
  int n0 = blockIdx.x * 128;

  f32x4 acc[2][4];
#pragma unroll
  for (int i = 0; i < 2; i++)
#pragma unroll
    for (int j = 0; j < 4; j++)
#pragma unroll
      for (int e = 0; e < 4; e++) acc[i][j][e] = 0.f;

  int lrow4 = lane >> 2, lkc = (lane & 3) * 8;
  int vml = t & 31, vd0 = (t >> 5) * 8;    // B-staging mapping

  for (int k0 = 0; k0 < KPAD; k0 += 64) {
    int nh = (KPAD - k0 >= 64) ? 2 : 1;
    for (int half = 0; half < nh; half++) {
      int kk = k0 + half * 32;
      // A: P rows via gl_lds16
#pragma unroll
      for (int rc = 0; rc < 2; rc++) {
        int c = w + rc * 4;
        int row = c * 16 + lrow4;
        int gn = n0 + row; if (gn > NN - 1) gn = NN - 1;
        gl_lds16(P + ((size_t)bh * NN + gn) * KPAD + kk + lkc, &As[half][c * 512]);
      }
      // B: V rows -> transposed LDS [d][m]
      {
        int m = kk + vml;
        u16 v8[8];
        if (m < NN) {
          const ushort4* vp = (const ushort4*)(qkv + (size_t)(b * NN + m) * QKVN + (4 + h) * DD + vd0);
          ushort4 lo = vp[0], hi = vp[1];
          v8[0] = lo.x; v8[1] = lo.y; v8[2] = lo.z; v8[3] = lo.w;
          v8[4] = hi.x; v8[5] = hi.y; v8[6] = hi.z; v8[7] = hi.w;
        } else {
#pragma unroll
          for (int j = 0; j < 8; j++) v8[j] = 0;
        }
#pragma unroll
        for (int j = 0; j < 8; j++) Bs[half][(vd0 + j) * 32 + vml] = v8[j];
      }
    }
    __syncthreads();
    int r16 = lane & 15, k8 = (lane >> 4) * 8;
    for (int half = 0; half < nh; half++) {
      s16x8 af[2], bfv[4];
#pragma unroll
      for (int s = 0; s < 2; s++)
        af[s] = *(const s16x8*)&As[half][(w * 32 + s * 16 + r16) * 32 + k8];
#pragma unroll
      for (int s = 0; s < 4; s++)
        bfv[s] = *(const s16x8*)&Bs[half][(s * 16 + r16) * 32 + k8];
#pragma unroll
      for (int sm = 0; sm < 2; sm++)
#pragma unroll
        for (int sn = 0; sn < 4; sn++)
          acc[sm][sn] = __builtin_amdgcn_mfma_f32_16x16x32_bf16(af[sm], bfv[sn], acc[sm][sn], 0, 0, 0);
    }
    __syncthreads();
  }
  int quad = lane >> 4, col = lane & 15;
#pragma unroll
  for (int sn = 0; sn < 4; sn++) {
    int gd = sn * 16 + col;                         // d
#pragma unroll
    for (int sm = 0; sm < 2; sm++) {
      int gnb = n0 + w * 32 + sm * 16 + quad * 4;   // n
#pragma unroll
      for (int i = 0; i < 4; i++) {
        int gn = gnb + i;
        if (gn < NN)
          aout[(size_t)(b * NN + gn) * CC + h * DD + gd] = f2bf(acc[sm][sn][i]);
      }
    }
  }
}

extern "C" void kernel_launch(void* const* d_in, const int* in_sizes, int n_in,
                              void* d_out, int out_size, void* d_ws, size_t ws_size,
                              hipStream_t stream) {
  const float* x     = (const float*)d_in[0];
  const float* qkv_w = (const float*)d_in[1];
  const float* qkv_b = (const float*)d_in[2];
  const float* masks = (const float*)d_in[3];
  const float* mproj = (const float*)d_in[4];
  const float* mbase = (const float*)d_in[5];
  const float* hpw   = (const float*)d_in[6];
  const float* hpb   = (const float*)d_in[7];
  const float* projw = (const float*)d_in[8];
  const float* projb = (const float*)d_in[9];

  char* ws = (char*)d_ws;
  size_t off = 0;
  auto alloc = [&](size_t bytes) {
    char* p = ws + off; off = (off + bytes + 255) & ~(size_t)255; return p;
  };
  // region1: xbf (19.4MB) -> att (21.0MB) -> aout (19.4MB), disjoint lifetimes
  char*  r1   = alloc((size_t)BB * 2 * NN * ATTS * 4);
  u16*   xbf  = (u16*)r1;
  float* att  = (float*)r1;
  u16*   aout = (u16*)r1;
  u16*   qkv  = (u16*)alloc((size_t)MROWS * QKVN * 2);          // 25.8 MB
  u16*   P    = (u16*)alloc((size_t)BB * HH * NN * KPAD * 2);   // 67.8 MB
  u16*   wt1  = (u16*)alloc((size_t)QKVN * CC * 2);             //  1.6 MB
  u16*   wt2  = (u16*)alloc((size_t)CC * CC * 2);               //  1.2 MB

  int n8 = MROWS * CC / 8;
  k_cvt_x<<<(n8 + 255) / 256, 256, 0, stream>>>(x, xbf, n8);
  k_transpose<<<dim3(QKVN / 32, CC / 32), 256, 0, stream>>>(qkv_w, wt1, CC, QKVN);
  k_transpose<<<dim3(CC / 32, CC / 32), 256, 0, stream>>>(projw, wt2, CC, CC);
  // qkv = x @ qkv_w + qkv_b  (bf16 out); 256^2 tiles, counted-vmcnt pipeline
  k_gemm_bt<<<dim3((MROWS + 255) / 256, QKVN / 256), 512, 0, stream>>>(
      xbf, wt1, qkv_b, qkv, MROWS, QKVN, CC, 1);
  // att[bg][n][m] = SCALE * q.k
  k_qk<<<dim3(2, 2, BB * 2), 256, 0, stream>>>(qkv, att);
  // P[b][h][n][m] (bf16, softmaxed)
  k_softmax_p<<<dim3(NN, BB), 256, 0, stream>>>(att, masks, mproj, mbase, hpw, hpb, P);
  // aout[b][n][h*64+d] = P @ V
  k_pv<<<dim3(2, BB * HH), 256, 0, stream>>>(P, qkv, aout);
  // out = aout @ proj_w + proj_b  (f32 out); 256^2 tiles, counted-vmcnt pipeline
  k_gemm_bt<<<dim3((MROWS + 255) / 256, CC / 256), 512, 0, stream>>>(
      aout, wt2, projb, d_out, MROWS, CC, CC, 0);
}